// Round 1
// baseline (4933.183 us; speedup 1.0000x reference)
//
#include <hip/hip_runtime.h>
#include <math.h>

// ---------------------------------------------------------------------------
// InvariantSRModel: 8192 x 6 restarts x 25 Adam steps fitting a quaternion so
// that Wigner-D(l=4,6) applied to fixed templates S4/S6 matches random targets.
//
// Math: D(a,b,c) = exp(a*X1) exp(b*X0) exp(g*X1)  (real-SH basis, from ref).
//   exp(th*X1) is a block rotation: pair (l-m, l+m) rotates by m*th.
//   exp(b*X0)  = J * exp(b*X1) * J,  J = exp((pi/sqrt2)(X0+X1))  (pi-rotation
//   about the bisector axis; J^2 = I for integer l).  J4/J6 computed on device
//   in fp64 (scaling & squaring) each launch into d_ws.
// Gradient: forward-mode duals, 4 lanes per instance (one tangent seed each),
// replicating JAX edge semantics (clip tie -> 0.5 factor, where(isfinite),
// atan2 JVP NaN at (0,0) which deliberately kills start 0 like the reference).
// ---------------------------------------------------------------------------

#define TWOPI_F 6.283185307179586f
#define EPS_Q   1e-12f

struct Dual { float v; float d; };

__device__ __forceinline__ bool finitef(float x) {
    return ((__float_as_uint(x) & 0x7f800000u) != 0x7f800000u);
}

// _normalize_quat, value-only (isfinite -> 0, norm<EPS -> unit)
__device__ __forceinline__ void normalize_q(const float in[4], float out[4]) {
    float w[4];
#pragma unroll
    for (int j = 0; j < 4; ++j) w[j] = finitef(in[j]) ? in[j] : 0.0f;
    float n = sqrtf(w[0]*w[0] + w[1]*w[1] + w[2]*w[2] + w[3]*w[3]);
    if (n < EPS_Q) {
        out[0] = 1.0f; out[1] = 0.0f; out[2] = 0.0f; out[3] = 0.0f;
    } else {
        float mx = fmaxf(n, EPS_Q);
#pragma unroll
        for (int j = 0; j < 4; ++j) out[j] = w[j] / mx;
    }
}

__device__ __forceinline__ void fix_sign(float q[4]) {
    if (q[0] < 0.0f) {
#pragma unroll
        for (int j = 0; j < 4; ++j) q[j] = -q[j];
    }
}

// jnp.clip(x,-1,1) dual with lax balanced-eq tie rule (tie -> 0.5 * tangent)
__device__ __forceinline__ Dual dclip(Dual x) {
    Dual t1;
    if (x.v > -1.0f)            t1 = x;
    else if (x.v == -1.0f)      t1 = Dual{x.v, 0.5f * x.d};
    else                        t1 = Dual{-1.0f, 0.0f};
    Dual t2;
    if (t1.v < 1.0f)            t2 = t1;
    else if (t1.v == 1.0f)      t2 = Dual{t1.v, 0.5f * t1.d};
    else                        t2 = Dual{1.0f, 0.0f};
    return t2;
}

// RotY block rotation applied to dual vector t[2L+1]; pair (L-m, L+m) by m*th.
template <int L>
__device__ __forceinline__ void roty_apply(Dual* t, const float* cs, const float* sn, float thd) {
#pragma unroll
    for (int m = 1; m <= L; ++m) {
        float cv = cs[m-1], sv = sn[m-1];
        float cd = -(float)m * sv * thd;
        float sd =  (float)m * cv * thd;
        Dual lo = t[L-m], hi = t[L+m];
        t[L-m].v = cv*lo.v + sv*hi.v;
        t[L-m].d = cv*lo.d + cd*lo.v + sv*hi.d + sd*hi.v;
        t[L+m].v = cv*hi.v - sv*lo.v;
        t[L+m].d = cv*hi.d + cd*hi.v - sv*lo.d - sd*lo.v;
    }
}

template <int N>
__device__ __forceinline__ void matvec_apply(Dual* t, const float* Jm) {
    float ov[N], od[N];
#pragma unroll
    for (int r = 0; r < N; ++r) {
        float sv = 0.0f, sd = 0.0f;
#pragma unroll
        for (int c = 0; c < N; ++c) {
            float jv = Jm[r*N + c];
            sv = fmaf(jv, t[c].v, sv);
            sd = fmaf(jv, t[c].d, sd);
        }
        ov[r] = sv; od[r] = sd;
    }
#pragma unroll
    for (int r = 0; r < N; ++r) { t[r].v = ov[r]; t[r].d = od[r]; }
}

// Full loss + directional derivative wrt u[seed]. Also outputs q = fix_sign(normalize(u)).
__device__ void eval_loss(const float uin[4], int seed,
                          const float* __restrict__ J4s, const float* __restrict__ J6s,
                          const float* __restrict__ tgt4, const float* __restrict__ tgt6,
                          float& loss_out, float& dloss_out, float qv[4])
{
    // ---- q = fix_sign(normalize(u)) with tangent ----
    Dual q[4];
    {
        float w[4], wd[4];
#pragma unroll
        for (int j = 0; j < 4; ++j) {
            bool f = finitef(uin[j]);
            w[j]  = f ? uin[j] : 0.0f;
            wd[j] = (f && (j == seed)) ? 1.0f : 0.0f;
        }
        float ss = w[0]*w[0] + w[1]*w[1] + w[2]*w[2] + w[3]*w[3];
        float n  = sqrtf(ss);
        if (n < EPS_Q) {
            q[0] = Dual{1.f, 0.f}; q[1] = Dual{0.f, 0.f};
            q[2] = Dual{0.f, 0.f}; q[3] = Dual{0.f, 0.f};
        } else {
            float nd = (w[0]*wd[0] + w[1]*wd[1] + w[2]*wd[2] + w[3]*wd[3]) / n;
            float mx = fmaxf(n, EPS_Q);
            float mxd = nd;  // n > EPS here
#pragma unroll
            for (int j = 0; j < 4; ++j) {
                q[j].v = w[j] / mx;
                q[j].d = wd[j] / mx - (w[j] * mxd) / (mx * mx);
            }
        }
        if (q[0].v < 0.0f) {
#pragma unroll
            for (int j = 0; j < 4; ++j) { q[j].v = -q[j].v; q[j].d = -q[j].d; }
        }
    }
#pragma unroll
    for (int j = 0; j < 4; ++j) qv[j] = q[j].v;

    // ---- rotation matrix entries (only the 7 we need) ----
    Dual W = q[0], X = q[1], Y = q[2], Z = q[3];
    auto mulD = [](Dual a, Dual b) { return Dual{a.v*b.v, a.v*b.d + a.d*b.v}; };
    Dual xx = mulD(X,X), yy = mulD(Y,Y), zz = mulD(Z,Z);
    Dual xy = mulD(X,Y), xz = mulD(X,Z), yz = mulD(Y,Z);
    Dual wx = mulD(W,X), wy = mulD(W,Y), wz = mulD(W,Z);
    Dual R00{1.f - 2.f*(yy.v+zz.v), -2.f*(yy.d+zz.d)};
    Dual R01{2.f*(xy.v-wz.v),        2.f*(xy.d-wz.d)};
    Dual R02{2.f*(xz.v+wy.v),        2.f*(xz.d+wy.d)};
    Dual R11{1.f - 2.f*(xx.v+zz.v), -2.f*(xx.d+zz.d)};
    Dual R21{2.f*(yz.v+wx.v),        2.f*(yz.d+wx.d)};
    Dual R20{2.f*(xz.v-wy.v),        2.f*(xz.d-wy.d)};
    Dual R22{1.f - 2.f*(xx.v+yy.v), -2.f*(xx.d+yy.d)};

    // ---- matrix_to_angles ----
    float ss2 = R01.v*R01.v + R11.v*R11.v + R21.v*R21.v;
    float n2  = sqrtf(ss2);
    float n2d = (R01.v*R01.d + R11.v*R11.d + R21.v*R21.d) / n2;
    float mx2  = fmaxf(n2, 1e-12f);
    float mx2d = (n2 > 1e-12f) ? n2d : 0.0f;
    auto divByN = [&](Dual a) { return Dual{a.v/mx2, a.d/mx2 - (a.v*mx2d)/(mx2*mx2)}; };
    Dual v0 = dclip(divByN(R01));
    Dual v1 = dclip(divByN(R11));
    Dual v2 = dclip(divByN(R21));

    Dual bA; bA.v = acosf(v1.v);
    bA.d = -v1.d / sqrtf(1.0f - v1.v*v1.v);          // inf/NaN at pole = ref semantics
    Dual aA; aA.v = atan2f(v0.v, v2.v);
    aA.d = (v2.v*v0.d - v0.v*v2.d) / (v0.v*v0.v + v2.v*v2.v);  // NaN at (0,0) = ref

    float sav, cav; sincosf(aA.v, &sav, &cav);
    Dual ca{cav, -sav*aA.d}, sa{sav, cav*aA.d};

    Dual ynum{ca.v*R02.v - sa.v*R22.v,
              ca.v*R02.d + ca.d*R02.v - sa.v*R22.d - sa.d*R22.v};
    Dual xden{ca.v*R00.v - sa.v*R20.v,
              ca.v*R00.d + ca.d*R00.v - sa.v*R20.d - sa.d*R20.v};
    Dual cC; cC.v = atan2f(ynum.v, xden.v);
    cC.d = (xden.v*ynum.d - ynum.v*xden.d) / (ynum.v*ynum.v + xden.v*xden.v);

    // ---- mod 2pi (XLA rem + fixup) ----
    auto dmod = [](Dual x) {
        float r = fmodf(x.v, TWOPI_F);
        if (r < 0.0f) r += TWOPI_F;
        return Dual{r, x.d};
    };
    Dual am = dmod(aA), bm = dmod(bA), gm = dmod(cC);

    // ---- trig tables m = 1..6 for the three angles ----
    float cAa[6], sAa[6], cBa[6], sBa[6], cGa[6], sGa[6];
#pragma unroll
    for (int m = 1; m <= 6; ++m) {
        sincosf((float)m * am.v, &sAa[m-1], &cAa[m-1]);
        sincosf((float)m * bm.v, &sBa[m-1], &cBa[m-1]);
        sincosf((float)m * gm.v, &sGa[m-1], &cGa[m-1]);
    }

    // ---- l = 4 chain: pred = RotY(a) J4 RotY(b) J4 RotY(g) S4 ----
    Dual t4[9];
#pragma unroll
    for (int i = 0; i < 9; ++i) t4[i] = Dual{0.f, 0.f};
    t4[4].v = 0.7638f; t4[8].v = 0.6455f;
    roty_apply<4>(t4, cGa, sGa, gm.d);
    matvec_apply<9>(t4, J4s);
    roty_apply<4>(t4, cBa, sBa, bm.d);
    matvec_apply<9>(t4, J4s);
    roty_apply<4>(t4, cAa, sAa, am.d);
    float s4 = 0.f, g4 = 0.f;
#pragma unroll
    for (int i = 0; i < 9; ++i) {
        float d = t4[i].v - tgt4[i];
        s4 += d * d; g4 += d * t4[i].d;
    }

    // ---- l = 6 chain ----
    Dual t6[13];
#pragma unroll
    for (int i = 0; i < 13; ++i) t6[i] = Dual{0.f, 0.f};
    t6[6].v = 0.3536f; t6[10].v = -0.9354f;
    roty_apply<6>(t6, cGa, sGa, gm.d);
    matvec_apply<13>(t6, J6s);
    roty_apply<6>(t6, cBa, sBa, bm.d);
    matvec_apply<13>(t6, J6s);
    roty_apply<6>(t6, cAa, sAa, am.d);
    float s6 = 0.f, g6 = 0.f;
#pragma unroll
    for (int i = 0; i < 13; ++i) {
        float d = t6[i].v - tgt6[i];
        s6 += d * d; g6 += d * t6[i].d;
    }

    loss_out  = s4 / 9.0f + 0.5f * (s6 / 13.0f);
    dloss_out = 2.0f * g4 / 9.0f + 0.5f * (2.0f * g6 / 13.0f);
}

// ---------------------------------------------------------------------------
// Setup kernel: compute J_l = expm((pi/sqrt2)(X0r + X1r)) in fp64.
// block 0 -> l=4 (writes ws[0..80]), block 1 -> l=6 (writes ws[81..249]).
// ---------------------------------------------------------------------------
__global__ void setup_J_kernel(float* __restrict__ Jout) {
    const int l  = (blockIdx.x == 0) ? 4 : 6;
    const int n  = 2 * l + 1;
    const int nn = n * n;
    const int tid = threadIdx.x;

    __shared__ double Qre[169], Qim[169], A[169], E[169], T[169], Wm[169];

    for (int i = tid; i < nn; i += blockDim.x) { Qre[i] = 0.0; Qim[i] = 0.0; }
    __syncthreads();

    // Q matrix (global (-i)^l phase omitted: cancels in Q^H X Q)
    if (tid < n) {
        int i = tid, m = i - l;
        double inv = 0.70710678118654752440;
        if (m < 0) {
            Qre[i*n + (2*l - i)] = inv;
            Qim[i*n + i]         = -inv;
        } else if (m == 0) {
            Qre[i*n + l] = 1.0;
        } else {
            double sgn = (m & 1) ? -1.0 : 1.0;
            Qre[i*n + i]         = sgn * inv;
            Qim[i*n + (2*l - i)] = sgn * inv;
        }
    }
    __syncthreads();

    // M1 = X0c * Q   (X0c tridiagonal skew-symmetric) -> E(re), T(im)
    if (tid < nn) {
        int r = tid / n, c = tid % n;
        double jj = (double)(l * (l + 1));
        double ar = 0.0, ai = 0.0;
        if (r > 0) {
            double md = (double)(r - 1 - l);
            double sub = -0.5 * sqrt(jj - md * (md + 1.0));
            ar += sub * Qre[(r-1)*n + c]; ai += sub * Qim[(r-1)*n + c];
        }
        if (r < n - 1) {
            double md = (double)(r - l);
            double sup = 0.5 * sqrt(jj - md * (md + 1.0));
            ar += sup * Qre[(r+1)*n + c]; ai += sup * Qim[(r+1)*n + c];
        }
        E[tid] = ar; T[tid] = ai;
    }
    __syncthreads();

    // X0r = Re(Q^H M1) -> Wm
    if (tid < nn) {
        int r = tid / n, c = tid % n;
        double s = 0.0;
        for (int i = 0; i < n; ++i)
            s += Qre[i*n + r] * E[i*n + c] + Qim[i*n + r] * T[i*n + c];
        Wm[tid] = s;
    }
    __syncthreads();

    // A = (pi/sqrt2) * (X0r + X1r) / 256       (X1r[l-m,l+m]=+m, [l+m,l-m]=-m)
    if (tid < nn) {
        int r = tid / n, c = tid % n;
        double x1 = ((r + c) == 2*l && r != c) ? (double)(c - l) : 0.0;
        A[tid] = 2.2214414690791831235 * (Wm[tid] + x1) * (1.0 / 256.0);
    }
    __syncthreads();

    // E = T = I
    if (tid < nn) {
        int r = tid / n, c = tid % n;
        double idv = (r == c) ? 1.0 : 0.0;
        E[tid] = idv; T[tid] = idv;
    }
    __syncthreads();

    // Taylor: T = T*A/k; E += T   (k = 1..16)
    for (int k = 1; k <= 16; ++k) {
        double val = 0.0;
        if (tid < nn) {
            int r = tid / n, c = tid % n;
            for (int i = 0; i < n; ++i) val += T[r*n + i] * A[i*n + c];
            val /= (double)k;
        }
        __syncthreads();
        if (tid < nn) { T[tid] = val; E[tid] += val; }
        __syncthreads();
    }

    // 8 squarings: E = E*E
    for (int s = 0; s < 8; ++s) {
        double val = 0.0;
        if (tid < nn) {
            int r = tid / n, c = tid % n;
            for (int i = 0; i < n; ++i) val += E[r*n + i] * E[i*n + c];
        }
        __syncthreads();
        if (tid < nn) Wm[tid] = val;
        __syncthreads();
        if (tid < nn) E[tid] = Wm[tid];
        __syncthreads();
    }

    if (tid < nn) Jout[(l == 4 ? 0 : 81) + tid] = (float)E[tid];
}

// ---------------------------------------------------------------------------
// Main kernel: 192 threads = 48 instances (4 lanes each) = 8 batch elements.
// ---------------------------------------------------------------------------
__global__ __launch_bounds__(192) void opt_kernel(
    const float* __restrict__ f4, const float* __restrict__ f6,
    const float* __restrict__ qr, const float* __restrict__ Jg,
    float* __restrict__ out)
{
    __shared__ float J4s[81], J6s[169];
    __shared__ float tg4[8 * 9], tg6[8 * 13];
    __shared__ float selL[48], selQ[48 * 4];

    const int tid = threadIdx.x;
    for (int i = tid; i < 81;  i += 192) J4s[i] = Jg[i];
    for (int i = tid; i < 169; i += 192) J6s[i] = Jg[81 + i];
    for (int i = tid; i < 72;  i += 192) tg4[i] = f4[blockIdx.x * 72  + i];
    for (int i = tid; i < 104; i += 192) tg6[i] = f6[blockIdx.x * 104 + i];
    __syncthreads();

    const int inst = tid >> 2;          // 0..47
    const int lane = tid & 3;           // tangent seed / Adam component
    const int gi   = blockIdx.x * 48 + inst;
    const int e    = gi / 6;
    const int k    = gi % 6;
    const int eloc = inst / 6;          // 0..7
    const float* tgt4 = &tg4[eloc * 9];
    const float* tgt6 = &tg6[eloc * 13];

    // ---- init u = fix_sign(normalize(concat(first, normalize(q_rand)))) ----
    float u[4];
    {
        float t0[4];
        if (k == 0) {
            t0[0] = 1.0f; t0[1] = 0.0f; t0[2] = 0.0f; t0[3] = 0.0f;
        } else {
            float raw[4];
#pragma unroll
            for (int j = 0; j < 4; ++j) raw[j] = qr[(e * 5 + (k - 1)) * 4 + j];
            normalize_q(raw, t0);
        }
        normalize_q(t0, u);
        fix_sign(u);
    }

    float mAd = 0.0f, vAd = 0.0f;
    float b1p = 1.0f, b2p = 1.0f;
    float lossF = 0.0f, qf[4];

#pragma unroll 1
    for (int step = 0; step <= 25; ++step) {
        float loss, dl, qtmp[4];
        eval_loss(u, lane, J4s, J6s, tgt4, tgt6, loss, dl, qtmp);
        if (step == 25) {
            lossF = loss;
#pragma unroll
            for (int j = 0; j < 4; ++j) qf[j] = qtmp[j];
            break;
        }
        float g = dl * (1.0f / 49152.0f);   // jnp.mean over bsz*k instances
        b1p *= 0.9f; b2p *= 0.999f;
        mAd = 0.9f   * mAd + 0.1f   * g;
        vAd = 0.999f * vAd + 0.001f * g * g;
        float mh = mAd / (1.0f - b1p);
        float vh = vAd / (1.0f - b2p);
        float un = u[lane] - 0.08f * mh / (sqrtf(vh) + 1e-8f);
        int base = (tid & 60);              // lane-quad base within wave
#pragma unroll
        for (int j = 0; j < 4; ++j) u[j] = __shfl(un, base + j, 64);
    }

    if (lane == 0) {
        selL[inst] = lossF;
#pragma unroll
        for (int j = 0; j < 4; ++j) selQ[inst * 4 + j] = qf[j];
    }
    __syncthreads();

    // ---- per-element argmin over 6 starts + final fix_sign(normalize()) ----
    if (tid < 8) {
        int b0 = tid * 6, best = 0;
        float bl = selL[b0];
#pragma unroll
        for (int kk = 1; kk < 6; ++kk) {
            float v = selL[b0 + kk];
            if (v < bl) { bl = v; best = kk; }
        }
        float qi[4], qo[4];
#pragma unroll
        for (int j = 0; j < 4; ++j) qi[j] = selQ[(b0 + best) * 4 + j];
        normalize_q(qi, qo);
        fix_sign(qo);
        int eo = blockIdx.x * 8 + tid;
#pragma unroll
        for (int j = 0; j < 4; ++j) out[eo * 4 + j] = qo[j];
    }
}

extern "C" void kernel_launch(void* const* d_in, const int* in_sizes, int n_in,
                              void* d_out, int out_size, void* d_ws, size_t ws_size,
                              hipStream_t stream) {
    const float* f4 = (const float*)d_in[0];   // (8192, 9)
    const float* f6 = (const float*)d_in[1];   // (8192, 13)
    const float* qr = (const float*)d_in[2];   // (8192, 5, 4)
    float* out = (float*)d_out;                // (8192, 4)
    float* Jws = (float*)d_ws;                 // 250 floats: J4 (81) + J6 (169)

    setup_J_kernel<<<2, 256, 0, stream>>>(Jws);
    opt_kernel<<<1024, 192, 0, stream>>>(f4, f6, qr, Jws, out);
}

// Round 2
// 4155.021 us; speedup vs baseline: 1.1873x; 1.1873x over previous
//
#include <hip/hip_runtime.h>
#include <math.h>

// ---------------------------------------------------------------------------
// InvariantSRModel: 8192 x 6 restarts x 25 Adam steps fitting a quaternion so
// that Wigner-D(l=4,6) applied to fixed templates S4/S6 matches random targets.
//
// D(a,b,c) = RotY(a) J RotY(b) J RotY(g)  applied to sparse S (mat-vec only).
// J = exp((pi/sqrt2)(X0+X1)) computed on device in fp64 each launch (d_ws is
// re-poisoned). J is symmetric orthogonal (pi-rotation rep), J^2 = I.
// Gradient: forward-mode duals, 4 lanes per instance (one tangent seed each).
// All libm trig replaced by hand sincos (Cody-Waite + cephes polys) + angle
// addition recurrence for m=2..6 -- the Round-1 kernel spilled to scratch
// (4 GB HBM fetch/launch) because 19 inlined ocml sincosf reduction paths
// blew the register budget.
// ---------------------------------------------------------------------------

#define TWOPI_F 6.283185307179586f
#define EPS_Q   1e-12f

struct Dual { float v; float d; };

__device__ __forceinline__ bool finitef(float x) {
    return ((__float_as_uint(x) & 0x7f800000u) != 0x7f800000u);
}

// sincos valid for |x| <= ~16 (we use |x| <= 2pi). NaN in -> NaN out.
__device__ __forceinline__ void fast_sincos(float x, float& s, float& c) {
    float fk = rintf(x * 0.6366197723675814f);   // x * 2/pi
    int   q  = (int)fk;
    float r  = fmaf(-fk, 1.5703125f, x);
    r = fmaf(-fk, 4.837512969970703125e-4f, r);
    r = fmaf(-fk, 7.549789948768648e-8f, r);
    float z  = r * r;
    float sp = fmaf(fmaf(fmaf(-1.9515295891e-4f, z, 8.3321608736e-3f), z,
                         -1.6666654611e-1f), z * r, r);
    float cp = fmaf(fmaf(fmaf(2.443315711809948e-5f, z, -1.388731625493765e-3f), z,
                         4.166664568298827e-2f), z * z, fmaf(-0.5f, z, 1.0f));
    int qa = q & 3;
    float s0 = (qa & 1) ? cp : sp;
    float c0 = (qa & 1) ? sp : cp;
    if (qa == 1 || qa == 2) c0 = -c0;
    if (qa >= 2)            s0 = -s0;
    s = s0; c = c0;
}

// _normalize_quat, value-only (isfinite -> 0, norm<EPS -> unit)
__device__ __forceinline__ void normalize_q(const float in[4], float out[4]) {
    float w[4];
#pragma unroll
    for (int j = 0; j < 4; ++j) w[j] = finitef(in[j]) ? in[j] : 0.0f;
    float n = sqrtf(w[0]*w[0] + w[1]*w[1] + w[2]*w[2] + w[3]*w[3]);
    if (n < EPS_Q) {
        out[0] = 1.0f; out[1] = 0.0f; out[2] = 0.0f; out[3] = 0.0f;
    } else {
        float mx = fmaxf(n, EPS_Q);
#pragma unroll
        for (int j = 0; j < 4; ++j) out[j] = w[j] / mx;
    }
}

__device__ __forceinline__ void fix_sign(float q[4]) {
    if (q[0] < 0.0f) {
#pragma unroll
        for (int j = 0; j < 4; ++j) q[j] = -q[j];
    }
}

// jnp.clip(x,-1,1) dual with lax balanced-eq tie rule (tie -> 0.5 * tangent)
__device__ __forceinline__ Dual dclip(Dual x) {
    Dual t1;
    if (x.v > -1.0f)            t1 = x;
    else if (x.v == -1.0f)      t1 = Dual{x.v, 0.5f * x.d};
    else                        t1 = Dual{-1.0f, 0.0f};
    Dual t2;
    if (t1.v < 1.0f)            t2 = t1;
    else if (t1.v == 1.0f)      t2 = Dual{t1.v, 0.5f * t1.d};
    else                        t2 = Dual{1.0f, 0.0f};
    return t2;
}

// RotY block rotation on split (v,d) arrays; pair (L-m, L+m) rotates by m*th.
template <int L>
__device__ __forceinline__ void roty_vd(float* v, float* d,
                                        const float* cs, const float* sn, float thd) {
#pragma unroll
    for (int m = 1; m <= L; ++m) {
        float cv = cs[m-1], sv = sn[m-1];
        float cd = -(float)m * sv * thd;
        float sd =  (float)m * cv * thd;
        float lov = v[L-m], lod = d[L-m], hiv = v[L+m], hid = d[L+m];
        v[L-m] = cv*lov + sv*hiv;
        d[L-m] = cv*lod + cd*lov + sv*hid + sd*hiv;
        v[L+m] = cv*hiv - sv*lov;
        d[L+m] = cv*hid + cd*hiv - sv*lod - sd*lov;
    }
}

template <int N>
__device__ __forceinline__ void matvec_vd(const float* v, const float* d,
                                          float* ov, float* od,
                                          const float* __restrict__ Jm) {
#pragma unroll
    for (int r = 0; r < N; ++r) {
        float sv = 0.0f, sd = 0.0f;
#pragma unroll
        for (int c = 0; c < N; ++c) {
            float jv = Jm[r*N + c];
            sv = fmaf(jv, v[c], sv);
            sd = fmaf(jv, d[c], sd);
        }
        ov[r] = sv; od[r] = sd;
    }
}

// Full loss + directional derivative wrt u[seed]; also q = fix_sign(normalize(u)).
__device__ void eval_loss(const float uin[4], int seed,
                          const float* __restrict__ J4s, const float* __restrict__ J6s,
                          const float* __restrict__ tgt4, const float* __restrict__ tgt6,
                          float& loss_out, float& dloss_out, float qv[4])
{
    // ---- q = fix_sign(normalize(u)) with tangent ----
    Dual q[4];
    {
        float w[4], wd[4];
#pragma unroll
        for (int j = 0; j < 4; ++j) {
            bool f = finitef(uin[j]);
            w[j]  = f ? uin[j] : 0.0f;
            wd[j] = (f && (j == seed)) ? 1.0f : 0.0f;
        }
        float ss = w[0]*w[0] + w[1]*w[1] + w[2]*w[2] + w[3]*w[3];
        float n  = sqrtf(ss);
        if (n < EPS_Q) {
            q[0] = Dual{1.f, 0.f}; q[1] = Dual{0.f, 0.f};
            q[2] = Dual{0.f, 0.f}; q[3] = Dual{0.f, 0.f};
        } else {
            float nd = (w[0]*wd[0] + w[1]*wd[1] + w[2]*wd[2] + w[3]*wd[3]) / n;
            float mx = fmaxf(n, EPS_Q);
#pragma unroll
            for (int j = 0; j < 4; ++j) {
                q[j].v = w[j] / mx;
                q[j].d = wd[j] / mx - (w[j] * nd) / (mx * mx);
            }
        }
        if (q[0].v < 0.0f) {
#pragma unroll
            for (int j = 0; j < 4; ++j) { q[j].v = -q[j].v; q[j].d = -q[j].d; }
        }
    }
#pragma unroll
    for (int j = 0; j < 4; ++j) qv[j] = q[j].v;

    // ---- rotation matrix entries (only the 7 we need) ----
    Dual W = q[0], X = q[1], Y = q[2], Z = q[3];
    auto mulD = [](Dual a, Dual b) { return Dual{a.v*b.v, a.v*b.d + a.d*b.v}; };
    Dual xx = mulD(X,X), yy = mulD(Y,Y), zz = mulD(Z,Z);
    Dual xy = mulD(X,Y), xz = mulD(X,Z), yz = mulD(Y,Z);
    Dual wx = mulD(W,X), wy = mulD(W,Y), wz = mulD(W,Z);
    Dual R00{1.f - 2.f*(yy.v+zz.v), -2.f*(yy.d+zz.d)};
    Dual R01{2.f*(xy.v-wz.v),        2.f*(xy.d-wz.d)};
    Dual R02{2.f*(xz.v+wy.v),        2.f*(xz.d+wy.d)};
    Dual R11{1.f - 2.f*(xx.v+zz.v), -2.f*(xx.d+zz.d)};
    Dual R21{2.f*(yz.v+wx.v),        2.f*(yz.d+wx.d)};
    Dual R20{2.f*(xz.v-wy.v),        2.f*(xz.d-wy.d)};
    Dual R22{1.f - 2.f*(xx.v+yy.v), -2.f*(xx.d+yy.d)};

    // ---- matrix_to_angles ----
    float ss2 = R01.v*R01.v + R11.v*R11.v + R21.v*R21.v;
    float n2  = sqrtf(ss2);
    float n2d = (R01.v*R01.d + R11.v*R11.d + R21.v*R21.d) / n2;
    float mx2 = fmaxf(n2, 1e-12f);
    float mx2d = (n2 > 1e-12f) ? n2d : 0.0f;
    auto divByN = [&](Dual a) { return Dual{a.v/mx2, a.d/mx2 - (a.v*mx2d)/(mx2*mx2)}; };
    Dual v0 = dclip(divByN(R01));
    Dual v1 = dclip(divByN(R11));
    Dual v2 = dclip(divByN(R21));

    Dual bA; bA.v = acosf(v1.v);
    bA.d = -v1.d / sqrtf(1.0f - v1.v*v1.v);          // inf/NaN at pole = ref semantics
    Dual aA; aA.v = atan2f(v0.v, v2.v);
    aA.d = (v2.v*v0.d - v0.v*v2.d) / (v0.v*v0.v + v2.v*v2.v);  // NaN at (0,0) = ref

    float sav, cav;
    fast_sincos(aA.v, sav, cav);
    Dual ca{cav, -sav*aA.d}, sa{sav, cav*aA.d};

    Dual ynum{ca.v*R02.v - sa.v*R22.v,
              ca.v*R02.d + ca.d*R02.v - sa.v*R22.d - sa.d*R22.v};
    Dual xden{ca.v*R00.v - sa.v*R20.v,
              ca.v*R00.d + ca.d*R00.v - sa.v*R20.d - sa.d*R20.v};
    Dual cC; cC.v = atan2f(ynum.v, xden.v);
    cC.d = (xden.v*ynum.d - ynum.v*xden.d) / (ynum.v*ynum.v + xden.v*xden.v);

    // ---- jnp.mod(x, 2pi) for |x| <= pi: rem is identity, fixup adds 2pi if x<0.
    //      (NaN and -0.0 propagate exactly like lax.rem + where fixup.) ----
    float amv = (aA.v < 0.0f) ? aA.v + TWOPI_F : aA.v;
    float bmv = bA.v;                     // acos in [0,pi]
    float gmv = (cC.v < 0.0f) ? cC.v + TWOPI_F : cC.v;
    float amd = aA.d, bmd = bA.d, gmd = cC.d;

    // ---- base trig (hand sincos, small args only) ----
    float sa1, ca1, sb1, cb1, sg1, cg1;
    fast_sincos(amv, sa1, ca1);
    fast_sincos(bmv, sb1, cb1);
    fast_sincos(gmv, sg1, cg1);

    // ---- gamma stage: sparse S -> only the m=4 pair rotates ----
    float cg2 = cg1*cg1 - sg1*sg1, sg2 = 2.f*sg1*cg1;
    float cg4 = cg2*cg2 - sg2*sg2, sg4 = 2.f*sg2*cg2;
    float c4d = -4.f*sg4*gmd, s4d = 4.f*cg4*gmd;

    // l=4: nonzeros at {0,4,8} (d at {0,8}); 3-col matvec with J4
    float u4v[9], u4d[9];
    {
        const float hi = 0.6455f, ce = 0.7638f;
        float t0v = sg4*hi, t0d = s4d*hi;
        float t8v = cg4*hi, t8d = c4d*hi;
#pragma unroll
        for (int r = 0; r < 9; ++r) {
            float j0 = J4s[r*9+0], j4 = J4s[r*9+4], j8 = J4s[r*9+8];
            u4v[r] = fmaf(j0, t0v, fmaf(j4, ce, j8*t8v));
            u4d[r] = fmaf(j0, t0d, j8*t8d);
        }
    }
    // l=6: nonzeros at {2,6,10} (d at {2,10}); 3-col matvec with J6
    float u6v[13], u6d[13];
    {
        const float hi = -0.9354f, ce = 0.3536f;
        float t2v = sg4*hi,  t2d = s4d*hi;
        float t10v = cg4*hi, t10d = c4d*hi;
#pragma unroll
        for (int r = 0; r < 13; ++r) {
            float j2 = J6s[r*13+2], j6 = J6s[r*13+6], j10 = J6s[r*13+10];
            u6v[r] = fmaf(j2, t2v, fmaf(j6, ce, j10*t10v));
            u6d[r] = fmaf(j2, t2d, j10*t10d);
        }
    }

    // ---- beta stage ----
    float cT[6], sT[6];
    cT[0] = cb1; sT[0] = sb1;
#pragma unroll
    for (int m = 1; m < 6; ++m) {
        cT[m] = cT[m-1]*cb1 - sT[m-1]*sb1;
        sT[m] = sT[m-1]*cb1 + cT[m-1]*sb1;
    }
    roty_vd<4>(u4v, u4d, cT, sT, bmd);
    float p4v[9], p4d[9];
    matvec_vd<9>(u4v, u4d, p4v, p4d, J4s);
    roty_vd<6>(u6v, u6d, cT, sT, bmd);
    float p6v[13], p6d[13];
    matvec_vd<13>(u6v, u6d, p6v, p6d, J6s);

    // ---- alpha stage + reduce ----
    cT[0] = ca1; sT[0] = sa1;
#pragma unroll
    for (int m = 1; m < 6; ++m) {
        cT[m] = cT[m-1]*ca1 - sT[m-1]*sa1;
        sT[m] = sT[m-1]*ca1 + cT[m-1]*sa1;
    }
    roty_vd<4>(p4v, p4d, cT, sT, amd);
    float s4s = 0.f, g4s = 0.f;
#pragma unroll
    for (int i = 0; i < 9; ++i) {
        float d = p4v[i] - tgt4[i];
        s4s = fmaf(d, d, s4s); g4s = fmaf(d, p4d[i], g4s);
    }
    roty_vd<6>(p6v, p6d, cT, sT, amd);
    float s6s = 0.f, g6s = 0.f;
#pragma unroll
    for (int i = 0; i < 13; ++i) {
        float d = p6v[i] - tgt6[i];
        s6s = fmaf(d, d, s6s); g6s = fmaf(d, p6d[i], g6s);
    }

    loss_out  = s4s / 9.0f + 0.5f * (s6s / 13.0f);
    dloss_out = 2.0f * g4s / 9.0f + 0.5f * (2.0f * g6s / 13.0f);
}

// ---------------------------------------------------------------------------
// Setup kernel: J_l = expm((pi/sqrt2)(X0r + X1r)) in fp64 (scaling&squaring).
// block 0 -> l=4 (ws[0..80]), block 1 -> l=6 (ws[81..249]).
// ---------------------------------------------------------------------------
__global__ void setup_J_kernel(float* __restrict__ Jout) {
    const int l  = (blockIdx.x == 0) ? 4 : 6;
    const int n  = 2 * l + 1;
    const int nn = n * n;
    const int tid = threadIdx.x;

    __shared__ double Qre[169], Qim[169], A[169], E[169], T[169], Wm[169];

    for (int i = tid; i < nn; i += blockDim.x) { Qre[i] = 0.0; Qim[i] = 0.0; }
    __syncthreads();

    if (tid < n) {
        int i = tid, m = i - l;
        double inv = 0.70710678118654752440;
        if (m < 0) {
            Qre[i*n + (2*l - i)] = inv;
            Qim[i*n + i]         = -inv;
        } else if (m == 0) {
            Qre[i*n + l] = 1.0;
        } else {
            double sgn = (m & 1) ? -1.0 : 1.0;
            Qre[i*n + i]         = sgn * inv;
            Qim[i*n + (2*l - i)] = sgn * inv;
        }
    }
    __syncthreads();

    if (tid < nn) {
        int r = tid / n, c = tid % n;
        double jj = (double)(l * (l + 1));
        double ar = 0.0, ai = 0.0;
        if (r > 0) {
            double md = (double)(r - 1 - l);
            double sub = -0.5 * sqrt(jj - md * (md + 1.0));
            ar += sub * Qre[(r-1)*n + c]; ai += sub * Qim[(r-1)*n + c];
        }
        if (r < n - 1) {
            double md = (double)(r - l);
            double sup = 0.5 * sqrt(jj - md * (md + 1.0));
            ar += sup * Qre[(r+1)*n + c]; ai += sup * Qim[(r+1)*n + c];
        }
        E[tid] = ar; T[tid] = ai;
    }
    __syncthreads();

    if (tid < nn) {
        int r = tid / n, c = tid % n;
        double s = 0.0;
        for (int i = 0; i < n; ++i)
            s += Qre[i*n + r] * E[i*n + c] + Qim[i*n + r] * T[i*n + c];
        Wm[tid] = s;
    }
    __syncthreads();

    if (tid < nn) {
        int r = tid / n, c = tid % n;
        double x1 = ((r + c) == 2*l && r != c) ? (double)(c - l) : 0.0;
        A[tid] = 2.2214414690791831235 * (Wm[tid] + x1) * (1.0 / 256.0);
    }
    __syncthreads();

    if (tid < nn) {
        int r = tid / n, c = tid % n;
        double idv = (r == c) ? 1.0 : 0.0;
        E[tid] = idv; T[tid] = idv;
    }
    __syncthreads();

    for (int k = 1; k <= 16; ++k) {
        double val = 0.0;
        if (tid < nn) {
            int r = tid / n, c = tid % n;
            for (int i = 0; i < n; ++i) val += T[r*n + i] * A[i*n + c];
            val /= (double)k;
        }
        __syncthreads();
        if (tid < nn) { T[tid] = val; E[tid] += val; }
        __syncthreads();
    }

    for (int s = 0; s < 8; ++s) {
        double val = 0.0;
        if (tid < nn) {
            int r = tid / n, c = tid % n;
            for (int i = 0; i < n; ++i) val += E[r*n + i] * E[i*n + c];
        }
        __syncthreads();
        if (tid < nn) Wm[tid] = val;
        __syncthreads();
        if (tid < nn) E[tid] = Wm[tid];
        __syncthreads();
    }

    if (tid < nn) Jout[(l == 4 ? 0 : 81) + tid] = (float)E[tid];
}

// ---------------------------------------------------------------------------
// Main kernel: 192 threads = 48 instances (4 lanes each) = 8 batch elements.
// ---------------------------------------------------------------------------
__global__ __launch_bounds__(192, 3) void opt_kernel(
    const float* __restrict__ f4, const float* __restrict__ f6,
    const float* __restrict__ qr, const float* __restrict__ Jg,
    float* __restrict__ out)
{
    __shared__ float J4s[81], J6s[169];
    __shared__ float tg4[8 * 9], tg6[8 * 13];
    __shared__ float selL[48], selQ[48 * 4];

    const int tid = threadIdx.x;
    for (int i = tid; i < 81;  i += 192) J4s[i] = Jg[i];
    for (int i = tid; i < 169; i += 192) J6s[i] = Jg[81 + i];
    for (int i = tid; i < 72;  i += 192) tg4[i] = f4[blockIdx.x * 72  + i];
    for (int i = tid; i < 104; i += 192) tg6[i] = f6[blockIdx.x * 104 + i];
    __syncthreads();

    const int inst = tid >> 2;          // 0..47
    const int lane = tid & 3;           // tangent seed / Adam component
    const int gi   = blockIdx.x * 48 + inst;
    const int e    = gi / 6;
    const int k    = gi % 6;
    const int eloc = inst / 6;          // 0..7
    const float* tgt4 = &tg4[eloc * 9];
    const float* tgt6 = &tg6[eloc * 13];

    // ---- init u = fix_sign(normalize(concat(first, normalize(q_rand)))) ----
    float u[4];
    {
        float t0[4];
        if (k == 0) {
            t0[0] = 1.0f; t0[1] = 0.0f; t0[2] = 0.0f; t0[3] = 0.0f;
        } else {
            float raw[4];
#pragma unroll
            for (int j = 0; j < 4; ++j) raw[j] = qr[(e * 5 + (k - 1)) * 4 + j];
            normalize_q(raw, t0);
        }
        normalize_q(t0, u);
        fix_sign(u);
    }

    float mAd = 0.0f, vAd = 0.0f;
    float b1p = 1.0f, b2p = 1.0f;
    float lossF = 0.0f, qf[4];

#pragma unroll 1
    for (int step = 0; step <= 25; ++step) {
        float loss, dl, qtmp[4];
        eval_loss(u, lane, J4s, J6s, tgt4, tgt6, loss, dl, qtmp);
        if (step == 25) {
            lossF = loss;
#pragma unroll
            for (int j = 0; j < 4; ++j) qf[j] = qtmp[j];
            break;
        }
        float g = dl * (1.0f / 49152.0f);   // jnp.mean over bsz*k instances
        b1p *= 0.9f; b2p *= 0.999f;
        mAd = 0.9f   * mAd + 0.1f   * g;
        vAd = 0.999f * vAd + 0.001f * g * g;
        float mh = mAd / (1.0f - b1p);
        float vh = vAd / (1.0f - b2p);
        float un = u[lane] - 0.08f * mh / (sqrtf(vh) + 1e-8f);
        int base = (tid & 60);              // lane-quad base within wave
#pragma unroll
        for (int j = 0; j < 4; ++j) u[j] = __shfl(un, base + j, 64);
    }

    if (lane == 0) {
        selL[inst] = lossF;
#pragma unroll
        for (int j = 0; j < 4; ++j) selQ[inst * 4 + j] = qf[j];
    }
    __syncthreads();

    // ---- per-element argmin over 6 starts + final fix_sign(normalize()) ----
    if (tid < 8) {
        int b0 = tid * 6, best = 0;
        float bl = selL[b0];
#pragma unroll
        for (int kk = 1; kk < 6; ++kk) {
            float v = selL[b0 + kk];
            if (v < bl) { bl = v; best = kk; }
        }
        float qi[4], qo[4];
#pragma unroll
        for (int j = 0; j < 4; ++j) qi[j] = selQ[(b0 + best) * 4 + j];
        normalize_q(qi, qo);
        fix_sign(qo);
        int eo = blockIdx.x * 8 + tid;
#pragma unroll
        for (int j = 0; j < 4; ++j) out[eo * 4 + j] = qo[j];
    }
}

extern "C" void kernel_launch(void* const* d_in, const int* in_sizes, int n_in,
                              void* d_out, int out_size, void* d_ws, size_t ws_size,
                              hipStream_t stream) {
    const float* f4 = (const float*)d_in[0];   // (8192, 9)
    const float* f6 = (const float*)d_in[1];   // (8192, 13)
    const float* qr = (const float*)d_in[2];   // (8192, 5, 4)
    float* out = (float*)d_out;                // (8192, 4)
    float* Jws = (float*)d_ws;                 // 250 floats: J4 (81) + J6 (169)

    setup_J_kernel<<<2, 256, 0, stream>>>(Jws);
    opt_kernel<<<1024, 192, 0, stream>>>(f4, f6, qr, Jws, out);
}

// Round 3
// 889.260 us; speedup vs baseline: 5.5475x; 4.6724x over previous
//
#include <hip/hip_runtime.h>
#include <math.h>

// ---------------------------------------------------------------------------
// InvariantSRModel: 8192 x 6 restarts x 25 Adam steps fitting a quaternion so
// that Wigner-D(l=4,6) applied to fixed templates S4/S6 matches random targets.
//
// D(a,b,c) = RotY(a) J RotY(b) J RotY(g) applied to sparse S (mat-vec only).
// J = exp((pi/sqrt2)(X0+X1)), fp64 scaling&squaring on device each launch.
// Gradient: forward-mode duals, 4 lanes per instance (one tangent seed each).
//
// Round-2 lesson: __launch_bounds__(192,3) set amdgpu-waves-per-eu min=3 and
// the RA chased 6 waves/EU (VGPR=84) by spilling every local array -> 10.6 GB
// of scratch traffic = 100% of runtime (VALUBusy 6%). Fix: plain
// __launch_bounds__(192) (no occupancy floor), __forceinline__ eval_loss with
// scalar-only ABI, and no runtime-indexed locals (u[lane] -> cndmask select).
// ---------------------------------------------------------------------------

#define TWOPI_F 6.283185307179586f
#define EPS_Q   1e-12f

struct Dual { float v; float d; };

__device__ __forceinline__ bool finitef(float x) {
    return ((__float_as_uint(x) & 0x7f800000u) != 0x7f800000u);
}

// sincos valid for |x| <= ~16 (we use |x| <= 2pi). NaN in -> NaN out.
__device__ __forceinline__ void fast_sincos(float x, float& s, float& c) {
    float fk = rintf(x * 0.6366197723675814f);   // x * 2/pi
    int   q  = (int)fk;
    float r  = fmaf(-fk, 1.5703125f, x);
    r = fmaf(-fk, 4.837512969970703125e-4f, r);
    r = fmaf(-fk, 7.549789948768648e-8f, r);
    float z  = r * r;
    float sp = fmaf(fmaf(fmaf(-1.9515295891e-4f, z, 8.3321608736e-3f), z,
                         -1.6666654611e-1f), z * r, r);
    float cp = fmaf(fmaf(fmaf(2.443315711809948e-5f, z, -1.388731625493765e-3f), z,
                         4.166664568298827e-2f), z * z, fmaf(-0.5f, z, 1.0f));
    int qa = q & 3;
    float s0 = (qa & 1) ? cp : sp;
    float c0 = (qa & 1) ? sp : cp;
    if (qa == 1 || qa == 2) c0 = -c0;
    if (qa >= 2)            s0 = -s0;
    s = s0; c = c0;
}

// _normalize_quat value-only, scalar ABI (isfinite -> 0, norm<EPS -> unit)
__device__ __forceinline__ void normalize4(float i0, float i1, float i2, float i3,
                                           float& o0, float& o1, float& o2, float& o3) {
    float a0 = finitef(i0) ? i0 : 0.0f;
    float a1 = finitef(i1) ? i1 : 0.0f;
    float a2 = finitef(i2) ? i2 : 0.0f;
    float a3 = finitef(i3) ? i3 : 0.0f;
    float n = sqrtf(a0*a0 + a1*a1 + a2*a2 + a3*a3);
    if (n < EPS_Q) { o0 = 1.0f; o1 = 0.0f; o2 = 0.0f; o3 = 0.0f; }
    else {
        float mx = fmaxf(n, EPS_Q);
        o0 = a0 / mx; o1 = a1 / mx; o2 = a2 / mx; o3 = a3 / mx;
    }
}

__device__ __forceinline__ void fixsign4(float& q0, float& q1, float& q2, float& q3) {
    if (q0 < 0.0f) { q0 = -q0; q1 = -q1; q2 = -q2; q3 = -q3; }
}

// jnp.clip(x,-1,1) dual with lax balanced-eq tie rule (tie -> 0.5 * tangent)
__device__ __forceinline__ Dual dclip(Dual x) {
    Dual t1;
    if (x.v > -1.0f)            t1 = x;
    else if (x.v == -1.0f)      t1 = Dual{x.v, 0.5f * x.d};
    else                        t1 = Dual{-1.0f, 0.0f};
    Dual t2;
    if (t1.v < 1.0f)            t2 = t1;
    else if (t1.v == 1.0f)      t2 = Dual{t1.v, 0.5f * t1.d};
    else                        t2 = Dual{1.0f, 0.0f};
    return t2;
}

// RotY block rotation on split (v,d) arrays; pair (L-m, L+m) rotates by m*th.
template <int L>
__device__ __forceinline__ void roty_vd(float* v, float* d,
                                        const float* cs, const float* sn, float thd) {
#pragma unroll
    for (int m = 1; m <= L; ++m) {
        float cv = cs[m-1], sv = sn[m-1];
        float cd = -(float)m * sv * thd;
        float sd =  (float)m * cv * thd;
        float lov = v[L-m], lod = d[L-m], hiv = v[L+m], hid = d[L+m];
        v[L-m] = cv*lov + sv*hiv;
        d[L-m] = cv*lod + cd*lov + sv*hid + sd*hiv;
        v[L+m] = cv*hiv - sv*lov;
        d[L+m] = cv*hid + cd*hiv - sv*lod - sd*lov;
    }
}

template <int N>
__device__ __forceinline__ void matvec_vd(const float* v, const float* d,
                                          float* ov, float* od,
                                          const float* __restrict__ Jm) {
#pragma unroll
    for (int r = 0; r < N; ++r) {
        float sv = 0.0f, sd = 0.0f;
#pragma unroll
        for (int c = 0; c < N; ++c) {
            float jv = Jm[r*N + c];
            sv = fmaf(jv, v[c], sv);
            sd = fmaf(jv, d[c], sd);
        }
        ov[r] = sv; od[r] = sd;
    }
}

// Full loss + directional derivative wrt u[seed]; also q = fix_sign(normalize(u)).
// Scalar-only ABI; must be inlined so everything lives in registers.
__device__ __forceinline__ void eval_loss(
    float uu0, float uu1, float uu2, float uu3, int seed,
    const float* __restrict__ J4s, const float* __restrict__ J6s,
    const float* __restrict__ tgt4, const float* __restrict__ tgt6,
    float& loss_out, float& dloss_out,
    float& q0o, float& q1o, float& q2o, float& q3o)
{
    // ---- q = fix_sign(normalize(u)) with tangent ----
    bool f0 = finitef(uu0), f1 = finitef(uu1), f2 = finitef(uu2), f3 = finitef(uu3);
    float w0 = f0 ? uu0 : 0.0f, w1 = f1 ? uu1 : 0.0f;
    float w2 = f2 ? uu2 : 0.0f, w3 = f3 ? uu3 : 0.0f;
    float wd0 = (f0 && seed == 0) ? 1.0f : 0.0f;
    float wd1 = (f1 && seed == 1) ? 1.0f : 0.0f;
    float wd2 = (f2 && seed == 2) ? 1.0f : 0.0f;
    float wd3 = (f3 && seed == 3) ? 1.0f : 0.0f;
    float ss = w0*w0 + w1*w1 + w2*w2 + w3*w3;
    float n  = sqrtf(ss);
    float q0v, q1v, q2v, q3v, q0d, q1d, q2d, q3d;
    if (n < EPS_Q) {
        q0v = 1.f; q1v = 0.f; q2v = 0.f; q3v = 0.f;
        q0d = 0.f; q1d = 0.f; q2d = 0.f; q3d = 0.f;
    } else {
        float nd = (w0*wd0 + w1*wd1 + w2*wd2 + w3*wd3) / n;
        float mx = fmaxf(n, EPS_Q);
        q0v = w0 / mx; q0d = wd0 / mx - (w0 * nd) / (mx * mx);
        q1v = w1 / mx; q1d = wd1 / mx - (w1 * nd) / (mx * mx);
        q2v = w2 / mx; q2d = wd2 / mx - (w2 * nd) / (mx * mx);
        q3v = w3 / mx; q3d = wd3 / mx - (w3 * nd) / (mx * mx);
    }
    if (q0v < 0.0f) {
        q0v = -q0v; q1v = -q1v; q2v = -q2v; q3v = -q3v;
        q0d = -q0d; q1d = -q1d; q2d = -q2d; q3d = -q3d;
    }
    q0o = q0v; q1o = q1v; q2o = q2v; q3o = q3v;

    // ---- rotation matrix entries (only the 7 we need) ----
    Dual W{q0v, q0d}, X{q1v, q1d}, Y{q2v, q2d}, Z{q3v, q3d};
    auto mulD = [](Dual a, Dual b) { return Dual{a.v*b.v, a.v*b.d + a.d*b.v}; };
    Dual xx = mulD(X,X), yy = mulD(Y,Y), zz = mulD(Z,Z);
    Dual xy = mulD(X,Y), xz = mulD(X,Z), yz = mulD(Y,Z);
    Dual wx = mulD(W,X), wy = mulD(W,Y), wz = mulD(W,Z);
    Dual R00{1.f - 2.f*(yy.v+zz.v), -2.f*(yy.d+zz.d)};
    Dual R01{2.f*(xy.v-wz.v),        2.f*(xy.d-wz.d)};
    Dual R02{2.f*(xz.v+wy.v),        2.f*(xz.d+wy.d)};
    Dual R11{1.f - 2.f*(xx.v+zz.v), -2.f*(xx.d+zz.d)};
    Dual R21{2.f*(yz.v+wx.v),        2.f*(yz.d+wx.d)};
    Dual R20{2.f*(xz.v-wy.v),        2.f*(xz.d-wy.d)};
    Dual R22{1.f - 2.f*(xx.v+yy.v), -2.f*(xx.d+yy.d)};

    // ---- matrix_to_angles ----
    float ss2 = R01.v*R01.v + R11.v*R11.v + R21.v*R21.v;
    float n2  = sqrtf(ss2);
    float n2d = (R01.v*R01.d + R11.v*R11.d + R21.v*R21.d) / n2;
    float mx2 = fmaxf(n2, 1e-12f);
    float mx2d = (n2 > 1e-12f) ? n2d : 0.0f;
    auto divByN = [&](Dual a) { return Dual{a.v/mx2, a.d/mx2 - (a.v*mx2d)/(mx2*mx2)}; };
    Dual v0 = dclip(divByN(R01));
    Dual v1 = dclip(divByN(R11));
    Dual v2 = dclip(divByN(R21));

    Dual bA; bA.v = acosf(v1.v);
    bA.d = -v1.d / sqrtf(1.0f - v1.v*v1.v);          // inf/NaN at pole = ref semantics
    Dual aA; aA.v = atan2f(v0.v, v2.v);
    aA.d = (v2.v*v0.d - v0.v*v2.d) / (v0.v*v0.v + v2.v*v2.v);  // NaN at (0,0) = ref

    float sav, cav;
    fast_sincos(aA.v, sav, cav);
    Dual ca{cav, -sav*aA.d}, sa{sav, cav*aA.d};

    Dual ynum{ca.v*R02.v - sa.v*R22.v,
              ca.v*R02.d + ca.d*R02.v - sa.v*R22.d - sa.d*R22.v};
    Dual xden{ca.v*R00.v - sa.v*R20.v,
              ca.v*R00.d + ca.d*R00.v - sa.v*R20.d - sa.d*R20.v};
    Dual cC; cC.v = atan2f(ynum.v, xden.v);
    cC.d = (xden.v*ynum.d - ynum.v*xden.d) / (ynum.v*ynum.v + xden.v*xden.v);

    // ---- jnp.mod(x,2pi) for |x| <= pi: rem identity + 2pi fixup if negative ----
    float amv = (aA.v < 0.0f) ? aA.v + TWOPI_F : aA.v;
    float bmv = bA.v;                     // acos in [0,pi]
    float gmv = (cC.v < 0.0f) ? cC.v + TWOPI_F : cC.v;
    float amd = aA.d, bmd = bA.d, gmd = cC.d;

    // ---- base trig ----
    float sa1, ca1, sb1, cb1, sg1, cg1;
    fast_sincos(amv, sa1, ca1);
    fast_sincos(bmv, sb1, cb1);
    fast_sincos(gmv, sg1, cg1);

    // ---- gamma stage: sparse S -> only the m=4 pair rotates ----
    float cg2 = cg1*cg1 - sg1*sg1, sg2 = 2.f*sg1*cg1;
    float cg4 = cg2*cg2 - sg2*sg2, sg4 = 2.f*sg2*cg2;
    float c4d = -4.f*sg4*gmd, s4d = 4.f*cg4*gmd;

    // l=4: nonzeros at {0,4,8} (d at {0,8}); 3-col matvec with J4
    float u4v[9], u4d[9];
    {
        const float hi = 0.6455f, ce = 0.7638f;
        float t0v = sg4*hi, t0d = s4d*hi;
        float t8v = cg4*hi, t8d = c4d*hi;
#pragma unroll
        for (int r = 0; r < 9; ++r) {
            float j0 = J4s[r*9+0], j4 = J4s[r*9+4], j8 = J4s[r*9+8];
            u4v[r] = fmaf(j0, t0v, fmaf(j4, ce, j8*t8v));
            u4d[r] = fmaf(j0, t0d, j8*t8d);
        }
    }
    // l=6: nonzeros at {2,6,10} (d at {2,10}); 3-col matvec with J6
    float u6v[13], u6d[13];
    {
        const float hi = -0.9354f, ce = 0.3536f;
        float t2v = sg4*hi,  t2d = s4d*hi;
        float t10v = cg4*hi, t10d = c4d*hi;
#pragma unroll
        for (int r = 0; r < 13; ++r) {
            float j2 = J6s[r*13+2], j6 = J6s[r*13+6], j10 = J6s[r*13+10];
            u6v[r] = fmaf(j2, t2v, fmaf(j6, ce, j10*t10v));
            u6d[r] = fmaf(j2, t2d, j10*t10d);
        }
    }

    // ---- beta stage ----
    float cT[6], sT[6];
    cT[0] = cb1; sT[0] = sb1;
#pragma unroll
    for (int m = 1; m < 6; ++m) {
        cT[m] = cT[m-1]*cb1 - sT[m-1]*sb1;
        sT[m] = sT[m-1]*cb1 + cT[m-1]*sb1;
    }
    roty_vd<4>(u4v, u4d, cT, sT, bmd);
    float p4v[9], p4d[9];
    matvec_vd<9>(u4v, u4d, p4v, p4d, J4s);
    roty_vd<6>(u6v, u6d, cT, sT, bmd);
    float p6v[13], p6d[13];
    matvec_vd<13>(u6v, u6d, p6v, p6d, J6s);

    // ---- alpha stage + reduce ----
    cT[0] = ca1; sT[0] = sa1;
#pragma unroll
    for (int m = 1; m < 6; ++m) {
        cT[m] = cT[m-1]*ca1 - sT[m-1]*sa1;
        sT[m] = sT[m-1]*ca1 + cT[m-1]*sa1;
    }
    roty_vd<4>(p4v, p4d, cT, sT, amd);
    float s4s = 0.f, g4s = 0.f;
#pragma unroll
    for (int i = 0; i < 9; ++i) {
        float d = p4v[i] - tgt4[i];
        s4s = fmaf(d, d, s4s); g4s = fmaf(d, p4d[i], g4s);
    }
    roty_vd<6>(p6v, p6d, cT, sT, amd);
    float s6s = 0.f, g6s = 0.f;
#pragma unroll
    for (int i = 0; i < 13; ++i) {
        float d = p6v[i] - tgt6[i];
        s6s = fmaf(d, d, s6s); g6s = fmaf(d, p6d[i], g6s);
    }

    loss_out  = s4s / 9.0f + 0.5f * (s6s / 13.0f);
    dloss_out = 2.0f * g4s / 9.0f + 0.5f * (2.0f * g6s / 13.0f);
}

// ---------------------------------------------------------------------------
// Setup kernel: J_l = expm((pi/sqrt2)(X0r + X1r)) in fp64 (scaling&squaring).
// block 0 -> l=4 (ws[0..80]), block 1 -> l=6 (ws[81..249]).
// ---------------------------------------------------------------------------
__global__ void setup_J_kernel(float* __restrict__ Jout) {
    const int l  = (blockIdx.x == 0) ? 4 : 6;
    const int n  = 2 * l + 1;
    const int nn = n * n;
    const int tid = threadIdx.x;

    __shared__ double Qre[169], Qim[169], A[169], E[169], T[169], Wm[169];

    for (int i = tid; i < nn; i += blockDim.x) { Qre[i] = 0.0; Qim[i] = 0.0; }
    __syncthreads();

    if (tid < n) {
        int i = tid, m = i - l;
        double inv = 0.70710678118654752440;
        if (m < 0) {
            Qre[i*n + (2*l - i)] = inv;
            Qim[i*n + i]         = -inv;
        } else if (m == 0) {
            Qre[i*n + l] = 1.0;
        } else {
            double sgn = (m & 1) ? -1.0 : 1.0;
            Qre[i*n + i]         = sgn * inv;
            Qim[i*n + (2*l - i)] = sgn * inv;
        }
    }
    __syncthreads();

    if (tid < nn) {
        int r = tid / n, c = tid % n;
        double jj = (double)(l * (l + 1));
        double ar = 0.0, ai = 0.0;
        if (r > 0) {
            double md = (double)(r - 1 - l);
            double sub = -0.5 * sqrt(jj - md * (md + 1.0));
            ar += sub * Qre[(r-1)*n + c]; ai += sub * Qim[(r-1)*n + c];
        }
        if (r < n - 1) {
            double md = (double)(r - l);
            double sup = 0.5 * sqrt(jj - md * (md + 1.0));
            ar += sup * Qre[(r+1)*n + c]; ai += sup * Qim[(r+1)*n + c];
        }
        E[tid] = ar; T[tid] = ai;
    }
    __syncthreads();

    if (tid < nn) {
        int r = tid / n, c = tid % n;
        double s = 0.0;
        for (int i = 0; i < n; ++i)
            s += Qre[i*n + r] * E[i*n + c] + Qim[i*n + r] * T[i*n + c];
        Wm[tid] = s;
    }
    __syncthreads();

    if (tid < nn) {
        int r = tid / n, c = tid % n;
        double x1 = ((r + c) == 2*l && r != c) ? (double)(c - l) : 0.0;
        A[tid] = 2.2214414690791831235 * (Wm[tid] + x1) * (1.0 / 256.0);
    }
    __syncthreads();

    if (tid < nn) {
        int r = tid / n, c = tid % n;
        double idv = (r == c) ? 1.0 : 0.0;
        E[tid] = idv; T[tid] = idv;
    }
    __syncthreads();

    for (int k = 1; k <= 16; ++k) {
        double val = 0.0;
        if (tid < nn) {
            int r = tid / n, c = tid % n;
            for (int i = 0; i < n; ++i) val += T[r*n + i] * A[i*n + c];
            val /= (double)k;
        }
        __syncthreads();
        if (tid < nn) { T[tid] = val; E[tid] += val; }
        __syncthreads();
    }

    for (int s = 0; s < 8; ++s) {
        double val = 0.0;
        if (tid < nn) {
            int r = tid / n, c = tid % n;
            for (int i = 0; i < n; ++i) val += E[r*n + i] * E[i*n + c];
        }
        __syncthreads();
        if (tid < nn) Wm[tid] = val;
        __syncthreads();
        if (tid < nn) E[tid] = Wm[tid];
        __syncthreads();
    }

    if (tid < nn) Jout[(l == 4 ? 0 : 81) + tid] = (float)E[tid];
}

// ---------------------------------------------------------------------------
// Main kernel: 192 threads = 48 instances (4 lanes each) = 8 batch elements.
// No occupancy floor: let the RA allocate what the math needs, zero spill.
// ---------------------------------------------------------------------------
__global__ __launch_bounds__(192) void opt_kernel(
    const float* __restrict__ f4, const float* __restrict__ f6,
    const float* __restrict__ qr, const float* __restrict__ Jg,
    float* __restrict__ out)
{
    __shared__ float J4s[81], J6s[169];
    __shared__ float tg4[8 * 9], tg6[8 * 13];
    __shared__ float selL[48], selQ[48 * 4];

    const int tid = threadIdx.x;
    for (int i = tid; i < 81;  i += 192) J4s[i] = Jg[i];
    for (int i = tid; i < 169; i += 192) J6s[i] = Jg[81 + i];
    for (int i = tid; i < 72;  i += 192) tg4[i] = f4[blockIdx.x * 72  + i];
    for (int i = tid; i < 104; i += 192) tg6[i] = f6[blockIdx.x * 104 + i];
    __syncthreads();

    const int inst = tid >> 2;          // 0..47
    const int lane = tid & 3;           // tangent seed / Adam component
    const int gi   = blockIdx.x * 48 + inst;
    const int e    = gi / 6;
    const int k    = gi % 6;
    const int eloc = inst / 6;          // 0..7
    const float* tgt4 = &tg4[eloc * 9];
    const float* tgt6 = &tg6[eloc * 13];

    // ---- init u = fix_sign(normalize(concat(first, normalize(q_rand)))) ----
    float u0, u1, u2, u3;
    {
        float t0, t1, t2, t3;
        if (k == 0) {
            t0 = 1.0f; t1 = 0.0f; t2 = 0.0f; t3 = 0.0f;
        } else {
            const float* rp = &qr[(e * 5 + (k - 1)) * 4];
            normalize4(rp[0], rp[1], rp[2], rp[3], t0, t1, t2, t3);
        }
        normalize4(t0, t1, t2, t3, u0, u1, u2, u3);
        fixsign4(u0, u1, u2, u3);
    }

    float mAd = 0.0f, vAd = 0.0f;
    float b1p = 1.0f, b2p = 1.0f;
    float lossF = 0.0f, qf0 = 0.f, qf1 = 0.f, qf2 = 0.f, qf3 = 0.f;
    const int base = tid & 60;          // lane-quad base within the 64-wide wave

#pragma unroll 1
    for (int step = 0; step <= 25; ++step) {
        float loss, dl, qt0, qt1, qt2, qt3;
        eval_loss(u0, u1, u2, u3, lane, J4s, J6s, tgt4, tgt6,
                  loss, dl, qt0, qt1, qt2, qt3);
        if (step == 25) {
            lossF = loss; qf0 = qt0; qf1 = qt1; qf2 = qt2; qf3 = qt3;
            break;
        }
        float g = dl * (1.0f / 49152.0f);   // jnp.mean over bsz*k instances
        b1p *= 0.9f; b2p *= 0.999f;
        mAd = 0.9f   * mAd + 0.1f   * g;
        vAd = 0.999f * vAd + 0.001f * g * g;
        float mh = mAd / (1.0f - b1p);
        float vh = vAd / (1.0f - b2p);
        float comp = (lane == 0) ? u0 : (lane == 1) ? u1 : (lane == 2) ? u2 : u3;
        float un = comp - 0.08f * mh / (sqrtf(vh) + 1e-8f);
        u0 = __shfl(un, base + 0, 64);
        u1 = __shfl(un, base + 1, 64);
        u2 = __shfl(un, base + 2, 64);
        u3 = __shfl(un, base + 3, 64);
    }

    if (lane == 0) {
        selL[inst] = lossF;
        selQ[inst * 4 + 0] = qf0; selQ[inst * 4 + 1] = qf1;
        selQ[inst * 4 + 2] = qf2; selQ[inst * 4 + 3] = qf3;
    }
    __syncthreads();

    // ---- per-element argmin over 6 starts + final fix_sign(normalize()) ----
    if (tid < 8) {
        int b0 = tid * 6, best = 0;
        float bl = selL[b0];
#pragma unroll
        for (int kk = 1; kk < 6; ++kk) {
            float v = selL[b0 + kk];
            if (v < bl) { bl = v; best = kk; }
        }
        float o0, o1, o2, o3;
        normalize4(selQ[(b0 + best) * 4 + 0], selQ[(b0 + best) * 4 + 1],
                   selQ[(b0 + best) * 4 + 2], selQ[(b0 + best) * 4 + 3],
                   o0, o1, o2, o3);
        fixsign4(o0, o1, o2, o3);
        int eo = blockIdx.x * 8 + tid;
        out[eo * 4 + 0] = o0; out[eo * 4 + 1] = o1;
        out[eo * 4 + 2] = o2; out[eo * 4 + 3] = o3;
    }
}

extern "C" void kernel_launch(void* const* d_in, const int* in_sizes, int n_in,
                              void* d_out, int out_size, void* d_ws, size_t ws_size,
                              hipStream_t stream) {
    const float* f4 = (const float*)d_in[0];   // (8192, 9)
    const float* f6 = (const float*)d_in[1];   // (8192, 13)
    const float* qr = (const float*)d_in[2];   // (8192, 5, 4)
    float* out = (float*)d_out;                // (8192, 4)
    float* Jws = (float*)d_ws;                 // 250 floats: J4 (81) + J6 (169)

    setup_J_kernel<<<2, 256, 0, stream>>>(Jws);
    opt_kernel<<<1024, 192, 0, stream>>>(f4, f6, qr, Jws, out);
}

// Round 4
// 521.505 us; speedup vs baseline: 9.4595x; 1.7052x over previous
//
#include <hip/hip_runtime.h>
#include <math.h>

// ---------------------------------------------------------------------------
// InvariantSRModel: 8192 x 6 restarts x 25 Adam steps fitting a quaternion so
// that Wigner-D(l=4,6) applied to fixed templates S4/S6 matches random targets.
//
// D(a,b,c) = RotY(a) J RotY(b) J RotY(g) applied to sparse S (mat-vec only).
// J = exp((pi/sqrt2)(X0+X1)), fp64 scaling&squaring on device each launch.
// Gradient: forward-mode duals, 4 lanes per instance (one tangent seed each).
//
// Round-3 lesson: VGPR still hit 256 + 120 MB spill stores because the l4/l6
// dual chains were interleaved and the loss/q outputs were live through the
// loop. This round: eval_grad (no loss, no q, no fix_sign -- R(q) is quadratic
// in q so the sign flip is loss-invariant) strictly sequential l4 then l6 with
// running-recurrence trig (no tables), plus a value-only eval_final.
// ---------------------------------------------------------------------------

#define TWOPI_F 6.283185307179586f
#define EPS_Q   1e-12f

__device__ __forceinline__ bool finitef(float x) {
    return ((__float_as_uint(x) & 0x7f800000u) != 0x7f800000u);
}

// sincos valid for |x| <= ~16 (we use |x| <= 2pi). NaN in -> NaN out.
__device__ __forceinline__ void fast_sincos(float x, float& s, float& c) {
    float fk = rintf(x * 0.6366197723675814f);   // x * 2/pi
    int   q  = (int)fk;
    float r  = fmaf(-fk, 1.5703125f, x);
    r = fmaf(-fk, 4.837512969970703125e-4f, r);
    r = fmaf(-fk, 7.549789948768648e-8f, r);
    float z  = r * r;
    float sp = fmaf(fmaf(fmaf(-1.9515295891e-4f, z, 8.3321608736e-3f), z,
                         -1.6666654611e-1f), z * r, r);
    float cp = fmaf(fmaf(fmaf(2.443315711809948e-5f, z, -1.388731625493765e-3f), z,
                         4.166664568298827e-2f), z * z, fmaf(-0.5f, z, 1.0f));
    int qa = q & 3;
    float s0 = (qa & 1) ? cp : sp;
    float c0 = (qa & 1) ? sp : cp;
    if (qa == 1 || qa == 2) c0 = -c0;
    if (qa >= 2)            s0 = -s0;
    s = s0; c = c0;
}

// _normalize_quat value-only, scalar ABI (isfinite -> 0, norm<EPS -> unit)
__device__ __forceinline__ void normalize4(float i0, float i1, float i2, float i3,
                                           float& o0, float& o1, float& o2, float& o3) {
    float a0 = finitef(i0) ? i0 : 0.0f;
    float a1 = finitef(i1) ? i1 : 0.0f;
    float a2 = finitef(i2) ? i2 : 0.0f;
    float a3 = finitef(i3) ? i3 : 0.0f;
    float n = sqrtf(a0*a0 + a1*a1 + a2*a2 + a3*a3);
    if (n < EPS_Q) { o0 = 1.0f; o1 = 0.0f; o2 = 0.0f; o3 = 0.0f; }
    else {
        float mx = fmaxf(n, EPS_Q);
        o0 = a0 / mx; o1 = a1 / mx; o2 = a2 / mx; o3 = a3 / mx;
    }
}

__device__ __forceinline__ void fixsign4(float& q0, float& q1, float& q2, float& q3) {
    if (q0 < 0.0f) { q0 = -q0; q1 = -q1; q2 = -q2; q3 = -q3; }
}

// ---- RotY block rotations with running angle-addition recurrence ----
template <int L>
__device__ __forceinline__ void roty_grad(float* v, float* d, float c1, float s1, float thd) {
    float cm = c1, sm = s1;
#pragma unroll
    for (int m = 1; m <= L; ++m) {
        float fm = (float)m;
        float cd = -fm * sm * thd;
        float sd =  fm * cm * thd;
        float lov = v[L-m], lod = d[L-m], hiv = v[L+m], hid = d[L+m];
        v[L-m] = cm*lov + sm*hiv;
        d[L-m] = cm*lod + cd*lov + sm*hid + sd*hiv;
        v[L+m] = cm*hiv - sm*lov;
        d[L+m] = cm*hid + cd*hiv - sm*lod - sd*lov;
        if (m < L) {
            float cn = cm*c1 - sm*s1;
            float sn = sm*c1 + cm*s1;
            cm = cn; sm = sn;
        }
    }
}

template <int L>
__device__ __forceinline__ void roty_val(float* v, float c1, float s1) {
    float cm = c1, sm = s1;
#pragma unroll
    for (int m = 1; m <= L; ++m) {
        float lov = v[L-m], hiv = v[L+m];
        v[L-m] = cm*lov + sm*hiv;
        v[L+m] = cm*hiv - sm*lov;
        if (m < L) {
            float cn = cm*c1 - sm*s1;
            float sn = sm*c1 + cm*s1;
            cm = cn; sm = sn;
        }
    }
}

template <int N>
__device__ __forceinline__ void matvec_grad(const float* v, const float* d,
                                            float* ov, float* od,
                                            const float* __restrict__ Jm) {
#pragma unroll
    for (int r = 0; r < N; ++r) {
        float sv = 0.0f, sd = 0.0f;
#pragma unroll
        for (int c = 0; c < N; ++c) {
            float jv = Jm[r*N + c];
            sv = fmaf(jv, v[c], sv);
            sd = fmaf(jv, d[c], sd);
        }
        ov[r] = sv; od[r] = sd;
    }
}

template <int N>
__device__ __forceinline__ void matvec_val(const float* v, float* ov,
                                           const float* __restrict__ Jm) {
#pragma unroll
    for (int r = 0; r < N; ++r) {
        float sv = 0.0f;
#pragma unroll
        for (int c = 0; c < N; ++c) sv = fmaf(Jm[r*N + c], v[c], sv);
        ov[r] = sv;
    }
}

// ---------------------------------------------------------------------------
// eval_grad: directional derivative of the per-instance SQUARED-ERROR SUMS
// (g4s, g6s combined into dl) wrt u[seed]. No loss value, no q output, no
// fix_sign (R(q) is quadratic in q: sign flip cancels in values AND tangents).
// ---------------------------------------------------------------------------
__device__ __forceinline__ float eval_grad(
    float uu0, float uu1, float uu2, float uu3, int seed,
    const float* __restrict__ J4s, const float* __restrict__ J6s,
    const float* __restrict__ tgt4, const float* __restrict__ tgt6)
{
    // ---- q = normalize(u) with tangent ----
    bool f0 = finitef(uu0), f1 = finitef(uu1), f2 = finitef(uu2), f3 = finitef(uu3);
    float w0 = f0 ? uu0 : 0.0f, w1 = f1 ? uu1 : 0.0f;
    float w2 = f2 ? uu2 : 0.0f, w3 = f3 ? uu3 : 0.0f;
    float wd0 = (f0 && seed == 0) ? 1.0f : 0.0f;
    float wd1 = (f1 && seed == 1) ? 1.0f : 0.0f;
    float wd2 = (f2 && seed == 2) ? 1.0f : 0.0f;
    float wd3 = (f3 && seed == 3) ? 1.0f : 0.0f;
    float ss = w0*w0 + w1*w1 + w2*w2 + w3*w3;
    float n  = sqrtf(ss);
    float q0v, q1v, q2v, q3v, q0d, q1d, q2d, q3d;
    if (n < EPS_Q) {
        q0v = 1.f; q1v = 0.f; q2v = 0.f; q3v = 0.f;
        q0d = 0.f; q1d = 0.f; q2d = 0.f; q3d = 0.f;
    } else {
        float nd = (w0*wd0 + w1*wd1 + w2*wd2 + w3*wd3) / n;
        float mx = fmaxf(n, EPS_Q);
        q0v = w0 / mx; q0d = wd0 / mx - (w0 * nd) / (mx * mx);
        q1v = w1 / mx; q1d = wd1 / mx - (w1 * nd) / (mx * mx);
        q2v = w2 / mx; q2d = wd2 / mx - (w2 * nd) / (mx * mx);
        q3v = w3 / mx; q3d = wd3 / mx - (w3 * nd) / (mx * mx);
    }

    // ---- the 7 rotation-matrix entries we need, with tangents ----
    float R00v = 1.f - 2.f*(q2v*q2v + q3v*q3v);
    float R00d = -4.f*(q2v*q2d + q3v*q3d);
    float R01v = 2.f*(q1v*q2v - q0v*q3v);
    float R01d = 2.f*(q1v*q2d + q1d*q2v - q0v*q3d - q0d*q3v);
    float R02v = 2.f*(q1v*q3v + q0v*q2v);
    float R02d = 2.f*(q1v*q3d + q1d*q3v + q0v*q2d + q0d*q2v);
    float R11v = 1.f - 2.f*(q1v*q1v + q3v*q3v);
    float R11d = -4.f*(q1v*q1d + q3v*q3d);
    float R21v = 2.f*(q2v*q3v + q0v*q1v);
    float R21d = 2.f*(q2v*q3d + q2d*q3v + q0v*q1d + q0d*q1v);
    float R20v = 2.f*(q1v*q3v - q0v*q2v);
    float R20d = 2.f*(q1v*q3d + q1d*q3v - q0v*q2d - q0d*q2v);
    float R22v = 1.f - 2.f*(q1v*q1v + q2v*q2v);
    float R22d = -4.f*(q1v*q1d + q2v*q2d);

    // ---- matrix_to_angles (duals) ----
    float ss2 = R01v*R01v + R11v*R11v + R21v*R21v;
    float n2  = sqrtf(ss2);
    float n2d = (R01v*R01d + R11v*R11d + R21v*R21d) / n2;
    float mx2 = fmaxf(n2, 1e-12f);
    float mx2d = (n2 > 1e-12f) ? n2d : 0.0f;
    // divByN + clip (lax balanced-eq tie rule) per component
    float v0v = R01v / mx2, v0d = R01d / mx2 - (R01v * mx2d) / (mx2 * mx2);
    float v1v = R11v / mx2, v1d = R11d / mx2 - (R11v * mx2d) / (mx2 * mx2);
    float v2v = R21v / mx2, v2d = R21d / mx2 - (R21v * mx2d) / (mx2 * mx2);
    {   // clip(v, -1, 1) with tie -> 0.5*tangent
        float tv, td;
        tv = v0v; td = v0d;
        if (!(tv > -1.0f)) { if (tv == -1.0f) td *= 0.5f; else { tv = -1.0f; td = 0.f; } }
        if (!(tv <  1.0f)) { if (tv ==  1.0f) td *= 0.5f; else { tv =  1.0f; td = 0.f; } }
        v0v = tv; v0d = td;
        tv = v1v; td = v1d;
        if (!(tv > -1.0f)) { if (tv == -1.0f) td *= 0.5f; else { tv = -1.0f; td = 0.f; } }
        if (!(tv <  1.0f)) { if (tv ==  1.0f) td *= 0.5f; else { tv =  1.0f; td = 0.f; } }
        v1v = tv; v1d = td;
        tv = v2v; td = v2d;
        if (!(tv > -1.0f)) { if (tv == -1.0f) td *= 0.5f; else { tv = -1.0f; td = 0.f; } }
        if (!(tv <  1.0f)) { if (tv ==  1.0f) td *= 0.5f; else { tv =  1.0f; td = 0.f; } }
        v2v = tv; v2d = td;
    }

    float bAv = acosf(v1v);
    float bAd = -v1d / sqrtf(1.0f - v1v*v1v);        // inf/NaN at pole = ref semantics
    float aAv = atan2f(v0v, v2v);
    float aAd = (v2v*v0d - v0v*v2d) / (v0v*v0v + v2v*v2v);  // NaN at (0,0) = ref

    float sav, cav;
    fast_sincos(aAv, sav, cav);
    float cad = -sav*aAd, sad = cav*aAd;

    float ynv = cav*R02v - sav*R22v;
    float ynd = cav*R02d + cad*R02v - sav*R22d - sad*R22v;
    float xdv = cav*R00v - sav*R20v;
    float xdd = cav*R00d + cad*R00v - sav*R20d - sad*R20v;
    float cCv = atan2f(ynv, xdv);
    float cCd = (xdv*ynd - ynv*xdd) / (ynv*ynv + xdv*xdv);

    // ---- jnp.mod(x,2pi) for |x| <= pi: rem identity + 2pi fixup if negative ----
    float amv = (aAv < 0.0f) ? aAv + TWOPI_F : aAv;
    float bmv = bAv;                       // acos in [0,pi]
    float gmv = (cCv < 0.0f) ? cCv + TWOPI_F : cCv;
    float amd = aAd, bmd = bAd, gmd = cCd;

    // ---- base trig ----
    float sa1, ca1, sb1, cb1, sg1, cg1;
    fast_sincos(amv, sa1, ca1);
    fast_sincos(bmv, sb1, cb1);
    fast_sincos(gmv, sg1, cg1);

    // ---- gamma stage: sparse S -> only the m=4 pair rotates ----
    float cg2 = cg1*cg1 - sg1*sg1, sg2 = 2.f*sg1*cg1;
    float cg4 = cg2*cg2 - sg2*sg2, sg4 = 2.f*sg2*cg2;
    float c4d = -4.f*sg4*gmd, s4d = 4.f*cg4*gmd;

    float dl;
    {   // ================= l = 4 chain =================
        float u4v[9], u4d[9];
        const float hi = 0.6455f, ce = 0.7638f;
        float t0v = sg4*hi, t0d = s4d*hi;
        float t8v = cg4*hi, t8d = c4d*hi;
#pragma unroll
        for (int r = 0; r < 9; ++r) {
            float j0 = J4s[r*9+0], j4 = J4s[r*9+4], j8 = J4s[r*9+8];
            u4v[r] = fmaf(j0, t0v, fmaf(j4, ce, j8*t8v));
            u4d[r] = fmaf(j0, t0d, j8*t8d);
        }
        roty_grad<4>(u4v, u4d, cb1, sb1, bmd);
        float p4v[9], p4d[9];
        matvec_grad<9>(u4v, u4d, p4v, p4d, J4s);
        roty_grad<4>(p4v, p4d, ca1, sa1, amd);
        float g4s = 0.f;
#pragma unroll
        for (int i = 0; i < 9; ++i) {
            float d = p4v[i] - tgt4[i];
            g4s = fmaf(d, p4d[i], g4s);
        }
        dl = 2.0f * g4s / 9.0f;
    }
    {   // ================= l = 6 chain =================
        float u6v[13], u6d[13];
        const float hi = -0.9354f, ce = 0.3536f;
        float t2v = sg4*hi,  t2d = s4d*hi;
        float t10v = cg4*hi, t10d = c4d*hi;
#pragma unroll
        for (int r = 0; r < 13; ++r) {
            float j2 = J6s[r*13+2], j6 = J6s[r*13+6], j10 = J6s[r*13+10];
            u6v[r] = fmaf(j2, t2v, fmaf(j6, ce, j10*t10v));
            u6d[r] = fmaf(j2, t2d, j10*t10d);
        }
        roty_grad<6>(u6v, u6d, cb1, sb1, bmd);
        float p6v[13], p6d[13];
        matvec_grad<13>(u6v, u6d, p6v, p6d, J6s);
        roty_grad<6>(p6v, p6d, ca1, sa1, amd);
        float g6s = 0.f;
#pragma unroll
        for (int i = 0; i < 13; ++i) {
            float d = p6v[i] - tgt6[i];
            g6s = fmaf(d, p6d[i], g6s);
        }
        dl += g6s / 13.0f;     // 0.5 * 2/13
    }
    return dl;
}

// ---------------------------------------------------------------------------
// eval_final: VALUE ONLY -- loss and q = fix_sign(normalize(u)).
// ---------------------------------------------------------------------------
__device__ __forceinline__ void eval_final(
    float uu0, float uu1, float uu2, float uu3,
    const float* __restrict__ J4s, const float* __restrict__ J6s,
    const float* __restrict__ tgt4, const float* __restrict__ tgt6,
    float& loss_out, float& q0o, float& q1o, float& q2o, float& q3o)
{
    float q0v, q1v, q2v, q3v;
    normalize4(uu0, uu1, uu2, uu3, q0v, q1v, q2v, q3v);
    fixsign4(q0v, q1v, q2v, q3v);
    q0o = q0v; q1o = q1v; q2o = q2v; q3o = q3v;

    float R00v = 1.f - 2.f*(q2v*q2v + q3v*q3v);
    float R01v = 2.f*(q1v*q2v - q0v*q3v);
    float R02v = 2.f*(q1v*q3v + q0v*q2v);
    float R11v = 1.f - 2.f*(q1v*q1v + q3v*q3v);
    float R21v = 2.f*(q2v*q3v + q0v*q1v);
    float R20v = 2.f*(q1v*q3v - q0v*q2v);
    float R22v = 1.f - 2.f*(q1v*q1v + q2v*q2v);

    float n2  = sqrtf(R01v*R01v + R11v*R11v + R21v*R21v);
    float mx2 = fmaxf(n2, 1e-12f);
    float v0v = fminf(fmaxf(R01v / mx2, -1.0f), 1.0f);
    float v1v = fminf(fmaxf(R11v / mx2, -1.0f), 1.0f);
    float v2v = fminf(fmaxf(R21v / mx2, -1.0f), 1.0f);
    // (value-level clip: jnp.clip == min(max(x,-1),1) for values; NaN cannot
    //  reach here when u is finite, and u all-NaN was mapped to unit q above)

    float bAv = acosf(v1v);
    float aAv = atan2f(v0v, v2v);
    float sav, cav;
    fast_sincos(aAv, sav, cav);
    float ynv = cav*R02v - sav*R22v;
    float xdv = cav*R00v - sav*R20v;
    float cCv = atan2f(ynv, xdv);

    float amv = (aAv < 0.0f) ? aAv + TWOPI_F : aAv;
    float bmv = bAv;
    float gmv = (cCv < 0.0f) ? cCv + TWOPI_F : cCv;

    float sa1, ca1, sb1, cb1, sg1, cg1;
    fast_sincos(amv, sa1, ca1);
    fast_sincos(bmv, sb1, cb1);
    fast_sincos(gmv, sg1, cg1);

    float cg2 = cg1*cg1 - sg1*sg1, sg2 = 2.f*sg1*cg1;
    float cg4 = cg2*cg2 - sg2*sg2, sg4 = 2.f*sg2*cg2;

    float loss;
    {   // l = 4
        float u4v[9];
        const float hi = 0.6455f, ce = 0.7638f;
        float t0v = sg4*hi, t8v = cg4*hi;
#pragma unroll
        for (int r = 0; r < 9; ++r)
            u4v[r] = fmaf(J4s[r*9+0], t0v, fmaf(J4s[r*9+4], ce, J4s[r*9+8]*t8v));
        roty_val<4>(u4v, cb1, sb1);
        float p4v[9];
        matvec_val<9>(u4v, p4v, J4s);
        roty_val<4>(p4v, ca1, sa1);
        float s4s = 0.f;
#pragma unroll
        for (int i = 0; i < 9; ++i) {
            float d = p4v[i] - tgt4[i];
            s4s = fmaf(d, d, s4s);
        }
        loss = s4s / 9.0f;
    }
    {   // l = 6
        float u6v[13];
        const float hi = -0.9354f, ce = 0.3536f;
        float t2v = sg4*hi, t10v = cg4*hi;
#pragma unroll
        for (int r = 0; r < 13; ++r)
            u6v[r] = fmaf(J6s[r*13+2], t2v, fmaf(J6s[r*13+6], ce, J6s[r*13+10]*t10v));
        roty_val<6>(u6v, cb1, sb1);
        float p6v[13];
        matvec_val<13>(u6v, p6v, J6s);
        roty_val<6>(p6v, ca1, sa1);
        float s6s = 0.f;
#pragma unroll
        for (int i = 0; i < 13; ++i) {
            float d = p6v[i] - tgt6[i];
            s6s = fmaf(d, d, s6s);
        }
        loss += 0.5f * (s6s / 13.0f);
    }
    loss_out = loss;
}

// ---------------------------------------------------------------------------
// Setup kernel: J_l = expm((pi/sqrt2)(X0r + X1r)) in fp64 (scaling&squaring).
// block 0 -> l=4 (ws[0..80]), block 1 -> l=6 (ws[81..249]).
// ---------------------------------------------------------------------------
__global__ void setup_J_kernel(float* __restrict__ Jout) {
    const int l  = (blockIdx.x == 0) ? 4 : 6;
    const int n  = 2 * l + 1;
    const int nn = n * n;
    const int tid = threadIdx.x;

    __shared__ double Qre[169], Qim[169], A[169], E[169], T[169], Wm[169];

    for (int i = tid; i < nn; i += blockDim.x) { Qre[i] = 0.0; Qim[i] = 0.0; }
    __syncthreads();

    if (tid < n) {
        int i = tid, m = i - l;
        double inv = 0.70710678118654752440;
        if (m < 0) {
            Qre[i*n + (2*l - i)] = inv;
            Qim[i*n + i]         = -inv;
        } else if (m == 0) {
            Qre[i*n + l] = 1.0;
        } else {
            double sgn = (m & 1) ? -1.0 : 1.0;
            Qre[i*n + i]         = sgn * inv;
            Qim[i*n + (2*l - i)] = sgn * inv;
        }
    }
    __syncthreads();

    if (tid < nn) {
        int r = tid / n, c = tid % n;
        double jj = (double)(l * (l + 1));
        double ar = 0.0, ai = 0.0;
        if (r > 0) {
            double md = (double)(r - 1 - l);
            double sub = -0.5 * sqrt(jj - md * (md + 1.0));
            ar += sub * Qre[(r-1)*n + c]; ai += sub * Qim[(r-1)*n + c];
        }
        if (r < n - 1) {
            double md = (double)(r - l);
            double sup = 0.5 * sqrt(jj - md * (md + 1.0));
            ar += sup * Qre[(r+1)*n + c]; ai += sup * Qim[(r+1)*n + c];
        }
        E[tid] = ar; T[tid] = ai;
    }
    __syncthreads();

    if (tid < nn) {
        int r = tid / n, c = tid % n;
        double s = 0.0;
        for (int i = 0; i < n; ++i)
            s += Qre[i*n + r] * E[i*n + c] + Qim[i*n + r] * T[i*n + c];
        Wm[tid] = s;
    }
    __syncthreads();

    if (tid < nn) {
        int r = tid / n, c = tid % n;
        double x1 = ((r + c) == 2*l && r != c) ? (double)(c - l) : 0.0;
        A[tid] = 2.2214414690791831235 * (Wm[tid] + x1) * (1.0 / 256.0);
    }
    __syncthreads();

    if (tid < nn) {
        int r = tid / n, c = tid % n;
        double idv = (r == c) ? 1.0 : 0.0;
        E[tid] = idv; T[tid] = idv;
    }
    __syncthreads();

    for (int k = 1; k <= 16; ++k) {
        double val = 0.0;
        if (tid < nn) {
            int r = tid / n, c = tid % n;
            for (int i = 0; i < n; ++i) val += T[r*n + i] * A[i*n + c];
            val /= (double)k;
        }
        __syncthreads();
        if (tid < nn) { T[tid] = val; E[tid] += val; }
        __syncthreads();
    }

    for (int s = 0; s < 8; ++s) {
        double val = 0.0;
        if (tid < nn) {
            int r = tid / n, c = tid % n;
            for (int i = 0; i < n; ++i) val += E[r*n + i] * E[i*n + c];
        }
        __syncthreads();
        if (tid < nn) Wm[tid] = val;
        __syncthreads();
        if (tid < nn) E[tid] = Wm[tid];
        __syncthreads();
    }

    if (tid < nn) Jout[(l == 4 ? 0 : 81) + tid] = (float)E[tid];
}

// ---------------------------------------------------------------------------
// Main kernel: 192 threads = 48 instances (4 lanes each) = 8 batch elements.
// ---------------------------------------------------------------------------
__global__ __launch_bounds__(192) void opt_kernel(
    const float* __restrict__ f4, const float* __restrict__ f6,
    const float* __restrict__ qr, const float* __restrict__ Jg,
    float* __restrict__ out)
{
    __shared__ float J4s[81], J6s[169];
    __shared__ float tg4[8 * 9], tg6[8 * 13];
    __shared__ float selL[48], selQ[48 * 4];

    const int tid = threadIdx.x;
    for (int i = tid; i < 81;  i += 192) J4s[i] = Jg[i];
    for (int i = tid; i < 169; i += 192) J6s[i] = Jg[81 + i];
    for (int i = tid; i < 72;  i += 192) tg4[i] = f4[blockIdx.x * 72  + i];
    for (int i = tid; i < 104; i += 192) tg6[i] = f6[blockIdx.x * 104 + i];
    __syncthreads();

    const int inst = tid >> 2;          // 0..47
    const int lane = tid & 3;           // tangent seed / Adam component
    const int gi   = blockIdx.x * 48 + inst;
    const int e    = gi / 6;
    const int k    = gi % 6;
    const int eloc = inst / 6;          // 0..7
    const float* tgt4 = &tg4[eloc * 9];
    const float* tgt6 = &tg6[eloc * 13];

    // ---- init u = fix_sign(normalize(concat(first, normalize(q_rand)))) ----
    float u0, u1, u2, u3;
    {
        float t0, t1, t2, t3;
        if (k == 0) {
            t0 = 1.0f; t1 = 0.0f; t2 = 0.0f; t3 = 0.0f;
        } else {
            const float* rp = &qr[(e * 5 + (k - 1)) * 4];
            normalize4(rp[0], rp[1], rp[2], rp[3], t0, t1, t2, t3);
        }
        normalize4(t0, t1, t2, t3, u0, u1, u2, u3);
        fixsign4(u0, u1, u2, u3);
    }

    float mAd = 0.0f, vAd = 0.0f;
    float b1p = 1.0f, b2p = 1.0f;
    const int base = tid & 60;          // lane-quad base within the 64-wide wave

#pragma unroll 1
    for (int step = 0; step < 25; ++step) {
        float dl = eval_grad(u0, u1, u2, u3, lane, J4s, J6s, tgt4, tgt6);
        float g = dl * (1.0f / 49152.0f);   // jnp.mean over bsz*k instances
        b1p *= 0.9f; b2p *= 0.999f;
        mAd = 0.9f   * mAd + 0.1f   * g;
        vAd = 0.999f * vAd + 0.001f * g * g;
        float mh = mAd / (1.0f - b1p);
        float vh = vAd / (1.0f - b2p);
        float comp = (lane == 0) ? u0 : (lane == 1) ? u1 : (lane == 2) ? u2 : u3;
        float un = comp - 0.08f * mh / (sqrtf(vh) + 1e-8f);
        u0 = __shfl(un, base + 0, 64);
        u1 = __shfl(un, base + 1, 64);
        u2 = __shfl(un, base + 2, 64);
        u3 = __shfl(un, base + 3, 64);
    }

    float lossF, qf0, qf1, qf2, qf3;
    eval_final(u0, u1, u2, u3, J4s, J6s, tgt4, tgt6, lossF, qf0, qf1, qf2, qf3);

    if (lane == 0) {
        selL[inst] = lossF;
        selQ[inst * 4 + 0] = qf0; selQ[inst * 4 + 1] = qf1;
        selQ[inst * 4 + 2] = qf2; selQ[inst * 4 + 3] = qf3;
    }
    __syncthreads();

    // ---- per-element argmin over 6 starts + final fix_sign(normalize()) ----
    if (tid < 8) {
        int b0 = tid * 6, best = 0;
        float bl = selL[b0];
#pragma unroll
        for (int kk = 1; kk < 6; ++kk) {
            float v = selL[b0 + kk];
            if (v < bl) { bl = v; best = kk; }
        }
        float o0, o1, o2, o3;
        normalize4(selQ[(b0 + best) * 4 + 0], selQ[(b0 + best) * 4 + 1],
                   selQ[(b0 + best) * 4 + 2], selQ[(b0 + best) * 4 + 3],
                   o0, o1, o2, o3);
        fixsign4(o0, o1, o2, o3);
        int eo = blockIdx.x * 8 + tid;
        out[eo * 4 + 0] = o0; out[eo * 4 + 1] = o1;
        out[eo * 4 + 2] = o2; out[eo * 4 + 3] = o3;
    }
}

extern "C" void kernel_launch(void* const* d_in, const int* in_sizes, int n_in,
                              void* d_out, int out_size, void* d_ws, size_t ws_size,
                              hipStream_t stream) {
    const float* f4 = (const float*)d_in[0];   // (8192, 9)
    const float* f6 = (const float*)d_in[1];   // (8192, 13)
    const float* qr = (const float*)d_in[2];   // (8192, 5, 4)
    float* out = (float*)d_out;                // (8192, 4)
    float* Jws = (float*)d_ws;                 // 250 floats: J4 (81) + J6 (169)

    setup_J_kernel<<<2, 256, 0, stream>>>(Jws);
    opt_kernel<<<1024, 192, 0, stream>>>(f4, f6, qr, Jws, out);
}

// Round 6
// 325.320 us; speedup vs baseline: 15.1641x; 1.6031x over previous
//
#include <hip/hip_runtime.h>
#include <math.h>

// ---------------------------------------------------------------------------
// InvariantSRModel: 8192 x 6 restarts x 25 Adam steps fitting a quaternion so
// that Wigner-D(l=4,6) applied to fixed templates S4/S6 matches random targets.
//
// D(a,b,c) = RotY(a) J RotY(b) J RotY(g) applied to sparse S (mat-vec only).
// J = exp((pi/sqrt2)(X0+X1)), fp64 scaling&squaring on device each launch.
//
// J STRUCTURE (round 6, corrected): e3nn is y-up; X1 generates rotation about
// y, X0 about x; azimuth phi = atan2(x, z) is measured from z. J is the
// pi-rotation about (x+y)/sqrt2 (swaps x<->y, negates z). It commutes with
// the mirror z->-z, whose diagonal action on real SHs is
//   s(m) = (-1)^m (m>=0),  (-1)^(|m|+1) (m<0)
// so J is block-diagonal under the INTERLEAVED partition
//   l=4: P+ = {1,3,4,6,8},        P- = {0,2,5,7}
//   l=6: P+ = {1,3,5,6,8,10,12},  P- = {0,2,4,7,9,11}
// (verified explicitly at l=1 where basis=(x,y,z), J=[[0,1,0],[1,0,0],[0,0,-1]]).
// Round-5's contiguous split was wrong -> absmax 1.98. This keeps the same
// 2x matvec savings with the correct index sets.
//
// Gradient: forward-mode duals, 4 lanes per instance (one tangent seed each).
// Lessons kept: no waves-per-EU floor (RA spills chasing it), scalar ABIs,
// no runtime-indexed locals, value-only final eval (fix_sign loss-invariant),
// hand sincos (ocml Payne-Hanek blew registers), J read from global with
// wave-uniform constant indices (scalarizable to s_load).
// ---------------------------------------------------------------------------

#define TWOPI_F 6.283185307179586f
#define EPS_Q   1e-12f

__device__ __forceinline__ bool finitef(float x) {
    return ((__float_as_uint(x) & 0x7f800000u) != 0x7f800000u);
}

// sincos valid for |x| <= ~16 (we use |x| <= 2pi). NaN in -> NaN out.
__device__ __forceinline__ void fast_sincos(float x, float& s, float& c) {
    float fk = rintf(x * 0.6366197723675814f);   // x * 2/pi
    int   q  = (int)fk;
    float r  = fmaf(-fk, 1.5703125f, x);
    r = fmaf(-fk, 4.837512969970703125e-4f, r);
    r = fmaf(-fk, 7.549789948768648e-8f, r);
    float z  = r * r;
    float sp = fmaf(fmaf(fmaf(-1.9515295891e-4f, z, 8.3321608736e-3f), z,
                         -1.6666654611e-1f), z * r, r);
    float cp = fmaf(fmaf(fmaf(2.443315711809948e-5f, z, -1.388731625493765e-3f), z,
                         4.166664568298827e-2f), z * z, fmaf(-0.5f, z, 1.0f));
    int qa = q & 3;
    float s0 = (qa & 1) ? cp : sp;
    float c0 = (qa & 1) ? sp : cp;
    if (qa == 1 || qa == 2) c0 = -c0;
    if (qa >= 2)            s0 = -s0;
    s = s0; c = c0;
}

// _normalize_quat value-only, scalar ABI (isfinite -> 0, norm<EPS -> unit)
__device__ __forceinline__ void normalize4(float i0, float i1, float i2, float i3,
                                           float& o0, float& o1, float& o2, float& o3) {
    float a0 = finitef(i0) ? i0 : 0.0f;
    float a1 = finitef(i1) ? i1 : 0.0f;
    float a2 = finitef(i2) ? i2 : 0.0f;
    float a3 = finitef(i3) ? i3 : 0.0f;
    float n = sqrtf(a0*a0 + a1*a1 + a2*a2 + a3*a3);
    if (n < EPS_Q) { o0 = 1.0f; o1 = 0.0f; o2 = 0.0f; o3 = 0.0f; }
    else {
        float mx = fmaxf(n, EPS_Q);
        o0 = a0 / mx; o1 = a1 / mx; o2 = a2 / mx; o3 = a3 / mx;
    }
}

__device__ __forceinline__ void fixsign4(float& q0, float& q1, float& q2, float& q3) {
    if (q0 < 0.0f) { q0 = -q0; q1 = -q1; q2 = -q2; q3 = -q3; }
}

// ---- RotY block rotations with running angle-addition recurrence ----
template <int L>
__device__ __forceinline__ void roty_grad(float* v, float* d, float c1, float s1, float thd) {
    float cm = c1, sm = s1;
#pragma unroll
    for (int m = 1; m <= L; ++m) {
        float fm = (float)m;
        float cd = -fm * sm * thd;
        float sd =  fm * cm * thd;
        float lov = v[L-m], lod = d[L-m], hiv = v[L+m], hid = d[L+m];
        v[L-m] = cm*lov + sm*hiv;
        d[L-m] = cm*lod + cd*lov + sm*hid + sd*hiv;
        v[L+m] = cm*hiv - sm*lov;
        d[L+m] = cm*hid + cd*hiv - sm*lod - sd*lov;
        if (m < L) {
            float cn = cm*c1 - sm*s1;
            float sn = sm*c1 + cm*s1;
            cm = cn; sm = sn;
        }
    }
}

template <int L>
__device__ __forceinline__ void roty_val(float* v, float c1, float s1) {
    float cm = c1, sm = s1;
#pragma unroll
    for (int m = 1; m <= L; ++m) {
        float lov = v[L-m], hiv = v[L+m];
        v[L-m] = cm*lov + sm*hiv;
        v[L+m] = cm*hiv - sm*lov;
        if (m < L) {
            float cn = cm*c1 - sm*s1;
            float sn = sm*c1 + cm*s1;
            cm = cn; sm = sn;
        }
    }
}

// Block-diagonal J matvec over an index LIST (compile-time), grad version.
template <int N, int K>
__device__ __forceinline__ void matvec_list_grad(const int (&idx)[K],
                                                 const float* v, const float* d,
                                                 float* ov, float* od,
                                                 const float* __restrict__ Jm) {
#pragma unroll
    for (int a = 0; a < K; ++a) {
        const int r = idx[a];
        float sv = 0.0f, sd = 0.0f;
#pragma unroll
        for (int b = 0; b < K; ++b) {
            const int c = idx[b];
            float jv = Jm[r*N + c];
            sv = fmaf(jv, v[c], sv);
            sd = fmaf(jv, d[c], sd);
        }
        ov[r] = sv; od[r] = sd;
    }
}

template <int N, int K>
__device__ __forceinline__ void matvec_list_val(const int (&idx)[K],
                                                const float* v, float* ov,
                                                const float* __restrict__ Jm) {
#pragma unroll
    for (int a = 0; a < K; ++a) {
        const int r = idx[a];
        float sv = 0.0f;
#pragma unroll
        for (int b = 0; b < K; ++b) {
            const int c = idx[b];
            sv = fmaf(Jm[r*N + c], v[c], sv);
        }
        ov[r] = sv;
    }
}

// ---------------------------------------------------------------------------
// eval_grad: directional derivative of the loss wrt u[seed]. No loss value,
// no q output, no fix_sign (R(q) quadratic in q: sign flip cancels).
// ---------------------------------------------------------------------------
__device__ __forceinline__ float eval_grad(
    float uu0, float uu1, float uu2, float uu3, int seed,
    const float* __restrict__ J4g, const float* __restrict__ J6g,
    const float* __restrict__ tgt4, const float* __restrict__ tgt6)
{
    // ---- q = normalize(u) with tangent ----
    bool f0 = finitef(uu0), f1 = finitef(uu1), f2 = finitef(uu2), f3 = finitef(uu3);
    float w0 = f0 ? uu0 : 0.0f, w1 = f1 ? uu1 : 0.0f;
    float w2 = f2 ? uu2 : 0.0f, w3 = f3 ? uu3 : 0.0f;
    float wd0 = (f0 && seed == 0) ? 1.0f : 0.0f;
    float wd1 = (f1 && seed == 1) ? 1.0f : 0.0f;
    float wd2 = (f2 && seed == 2) ? 1.0f : 0.0f;
    float wd3 = (f3 && seed == 3) ? 1.0f : 0.0f;
    float ss = w0*w0 + w1*w1 + w2*w2 + w3*w3;
    float n  = sqrtf(ss);
    float q0v, q1v, q2v, q3v, q0d, q1d, q2d, q3d;
    if (n < EPS_Q) {
        q0v = 1.f; q1v = 0.f; q2v = 0.f; q3v = 0.f;
        q0d = 0.f; q1d = 0.f; q2d = 0.f; q3d = 0.f;
    } else {
        float nd = (w0*wd0 + w1*wd1 + w2*wd2 + w3*wd3) / n;
        float mx = fmaxf(n, EPS_Q);
        q0v = w0 / mx; q0d = wd0 / mx - (w0 * nd) / (mx * mx);
        q1v = w1 / mx; q1d = wd1 / mx - (w1 * nd) / (mx * mx);
        q2v = w2 / mx; q2d = wd2 / mx - (w2 * nd) / (mx * mx);
        q3v = w3 / mx; q3d = wd3 / mx - (w3 * nd) / (mx * mx);
    }

    // ---- the 7 rotation-matrix entries we need, with tangents ----
    float R00v = 1.f - 2.f*(q2v*q2v + q3v*q3v);
    float R00d = -4.f*(q2v*q2d + q3v*q3d);
    float R01v = 2.f*(q1v*q2v - q0v*q3v);
    float R01d = 2.f*(q1v*q2d + q1d*q2v - q0v*q3d - q0d*q3v);
    float R02v = 2.f*(q1v*q3v + q0v*q2v);
    float R02d = 2.f*(q1v*q3d + q1d*q3v + q0v*q2d + q0d*q2v);
    float R11v = 1.f - 2.f*(q1v*q1v + q3v*q3v);
    float R11d = -4.f*(q1v*q1d + q3v*q3d);
    float R21v = 2.f*(q2v*q3v + q0v*q1v);
    float R21d = 2.f*(q2v*q3d + q2d*q3v + q0v*q1d + q0d*q1v);
    float R20v = 2.f*(q1v*q3v - q0v*q2v);
    float R20d = 2.f*(q1v*q3d + q1d*q3v - q0v*q2d - q0d*q2v);
    float R22v = 1.f - 2.f*(q1v*q1v + q2v*q2v);
    float R22d = -4.f*(q1v*q1d + q2v*q2d);

    // ---- matrix_to_angles (duals) ----
    float ss2 = R01v*R01v + R11v*R11v + R21v*R21v;
    float n2  = sqrtf(ss2);
    float n2d = (R01v*R01d + R11v*R11d + R21v*R21d) / n2;
    float mx2 = fmaxf(n2, 1e-12f);
    float mx2d = (n2 > 1e-12f) ? n2d : 0.0f;
    float v0v = R01v / mx2, v0d = R01d / mx2 - (R01v * mx2d) / (mx2 * mx2);
    float v1v = R11v / mx2, v1d = R11d / mx2 - (R11v * mx2d) / (mx2 * mx2);
    float v2v = R21v / mx2, v2d = R21d / mx2 - (R21v * mx2d) / (mx2 * mx2);
    {   // clip(v,-1,1) with lax balanced-eq tie rule (tie -> 0.5*tangent)
        float tv, td;
        tv = v0v; td = v0d;
        if (!(tv > -1.0f)) { if (tv == -1.0f) td *= 0.5f; else { tv = -1.0f; td = 0.f; } }
        if (!(tv <  1.0f)) { if (tv ==  1.0f) td *= 0.5f; else { tv =  1.0f; td = 0.f; } }
        v0v = tv; v0d = td;
        tv = v1v; td = v1d;
        if (!(tv > -1.0f)) { if (tv == -1.0f) td *= 0.5f; else { tv = -1.0f; td = 0.f; } }
        if (!(tv <  1.0f)) { if (tv ==  1.0f) td *= 0.5f; else { tv =  1.0f; td = 0.f; } }
        v1v = tv; v1d = td;
        tv = v2v; td = v2d;
        if (!(tv > -1.0f)) { if (tv == -1.0f) td *= 0.5f; else { tv = -1.0f; td = 0.f; } }
        if (!(tv <  1.0f)) { if (tv ==  1.0f) td *= 0.5f; else { tv =  1.0f; td = 0.f; } }
        v2v = tv; v2d = td;
    }

    float bAv = acosf(v1v);
    float bAd = -v1d / sqrtf(1.0f - v1v*v1v);        // inf/NaN at pole = ref semantics
    float aAv = atan2f(v0v, v2v);
    float aAd = (v2v*v0d - v0v*v2d) / (v0v*v0v + v2v*v2v);  // NaN at (0,0) = ref

    float sav, cav;
    fast_sincos(aAv, sav, cav);
    float cad = -sav*aAd, sad = cav*aAd;

    float ynv = cav*R02v - sav*R22v;
    float ynd = cav*R02d + cad*R02v - sav*R22d - sad*R22v;
    float xdv = cav*R00v - sav*R20v;
    float xdd = cav*R00d + cad*R00v - sav*R20d - sad*R20v;
    float cCv = atan2f(ynv, xdv);
    float cCd = (xdv*ynd - ynv*xdd) / (ynv*ynv + xdv*xdv);

    // ---- jnp.mod(x,2pi) for |x| <= pi: rem identity + 2pi fixup if negative ----
    float amv = (aAv < 0.0f) ? aAv + TWOPI_F : aAv;
    float bmv = bAv;                       // acos in [0,pi]
    float gmv = (cCv < 0.0f) ? cCv + TWOPI_F : cCv;
    float amd = aAd, bmd = bAd, gmd = cCd;

    // ---- base trig ----
    float sa1, ca1, sb1, cb1, sg1, cg1;
    fast_sincos(amv, sa1, ca1);
    fast_sincos(bmv, sb1, cb1);
    fast_sincos(gmv, sg1, cg1);

    // ---- gamma stage: sparse S -> only the m=4 pair rotates ----
    float cg2 = cg1*cg1 - sg1*sg1, sg2 = 2.f*sg1*cg1;
    float cg4 = cg2*cg2 - sg2*sg2, sg4 = 2.f*sg2*cg2;
    float c4d = -4.f*sg4*gmd, s4d = 4.f*cg4*gmd;

    constexpr int P4p[5] = {1,3,4,6,8};
    constexpr int P4m[4] = {0,2,5,7};
    constexpr int P6p[7] = {1,3,5,6,8,10,12};
    constexpr int P6m[6] = {0,2,4,7,9,11};

    float dl;
    {   // ================= l = 4 chain =================
        // gamma output nonzeros: i=0 (class -), i=4, i=8 (class +).
        float u4v[9], u4d[9];
        const float hi = 0.6455f, ce = 0.7638f;
        float t0v = sg4*hi, t0d = s4d*hi;
        float t8v = cg4*hi, t8d = c4d*hi;
#pragma unroll
        for (int a = 0; a < 4; ++a) {
            const int r = P4m[a];
            float j0 = J4g[r*9+0];
            u4v[r] = j0 * t0v;
            u4d[r] = j0 * t0d;
        }
#pragma unroll
        for (int a = 0; a < 5; ++a) {
            const int r = P4p[a];
            float j4 = J4g[r*9+4], j8 = J4g[r*9+8];
            u4v[r] = fmaf(j4, ce, j8*t8v);
            u4d[r] = j8 * t8d;
        }
        roty_grad<4>(u4v, u4d, cb1, sb1, bmd);
        float p4v[9], p4d[9];
        matvec_list_grad<9,4>(P4m, u4v, u4d, p4v, p4d, J4g);
        matvec_list_grad<9,5>(P4p, u4v, u4d, p4v, p4d, J4g);
        roty_grad<4>(p4v, p4d, ca1, sa1, amd);
        float g4s = 0.f;
#pragma unroll
        for (int i = 0; i < 9; ++i) {
            float d = p4v[i] - tgt4[i];
            g4s = fmaf(d, p4d[i], g4s);
        }
        dl = 2.0f * g4s / 9.0f;
    }
    {   // ================= l = 6 chain =================
        // gamma output nonzeros: i=2 (class -), i=6, i=10 (class +).
        float u6v[13], u6d[13];
        const float hi = -0.9354f, ce = 0.3536f;
        float t2v = sg4*hi,  t2d = s4d*hi;
        float t10v = cg4*hi, t10d = c4d*hi;
#pragma unroll
        for (int a = 0; a < 6; ++a) {
            const int r = P6m[a];
            float j2 = J6g[r*13+2];
            u6v[r] = j2 * t2v;
            u6d[r] = j2 * t2d;
        }
#pragma unroll
        for (int a = 0; a < 7; ++a) {
            const int r = P6p[a];
            float j6 = J6g[r*13+6], j10 = J6g[r*13+10];
            u6v[r] = fmaf(j6, ce, j10*t10v);
            u6d[r] = j10 * t10d;
        }
        roty_grad<6>(u6v, u6d, cb1, sb1, bmd);
        float p6v[13], p6d[13];
        matvec_list_grad<13,6>(P6m, u6v, u6d, p6v, p6d, J6g);
        matvec_list_grad<13,7>(P6p, u6v, u6d, p6v, p6d, J6g);
        roty_grad<6>(p6v, p6d, ca1, sa1, amd);
        float g6s = 0.f;
#pragma unroll
        for (int i = 0; i < 13; ++i) {
            float d = p6v[i] - tgt6[i];
            g6s = fmaf(d, p6d[i], g6s);
        }
        dl += g6s / 13.0f;     // 0.5 * 2/13
    }
    return dl;
}

// ---------------------------------------------------------------------------
// eval_final: VALUE ONLY -- loss and q = fix_sign(normalize(u)).
// ---------------------------------------------------------------------------
__device__ __forceinline__ void eval_final(
    float uu0, float uu1, float uu2, float uu3,
    const float* __restrict__ J4g, const float* __restrict__ J6g,
    const float* __restrict__ tgt4, const float* __restrict__ tgt6,
    float& loss_out, float& q0o, float& q1o, float& q2o, float& q3o)
{
    float q0v, q1v, q2v, q3v;
    normalize4(uu0, uu1, uu2, uu3, q0v, q1v, q2v, q3v);
    fixsign4(q0v, q1v, q2v, q3v);
    q0o = q0v; q1o = q1v; q2o = q2v; q3o = q3v;

    float R00v = 1.f - 2.f*(q2v*q2v + q3v*q3v);
    float R01v = 2.f*(q1v*q2v - q0v*q3v);
    float R02v = 2.f*(q1v*q3v + q0v*q2v);
    float R11v = 1.f - 2.f*(q1v*q1v + q3v*q3v);
    float R21v = 2.f*(q2v*q3v + q0v*q1v);
    float R20v = 2.f*(q1v*q3v - q0v*q2v);
    float R22v = 1.f - 2.f*(q1v*q1v + q2v*q2v);

    float n2  = sqrtf(R01v*R01v + R11v*R11v + R21v*R21v);
    float mx2 = fmaxf(n2, 1e-12f);
    float v0v = fminf(fmaxf(R01v / mx2, -1.0f), 1.0f);
    float v1v = fminf(fmaxf(R11v / mx2, -1.0f), 1.0f);
    float v2v = fminf(fmaxf(R21v / mx2, -1.0f), 1.0f);

    float bAv = acosf(v1v);
    float aAv = atan2f(v0v, v2v);
    float sav, cav;
    fast_sincos(aAv, sav, cav);
    float ynv = cav*R02v - sav*R22v;
    float xdv = cav*R00v - sav*R20v;
    float cCv = atan2f(ynv, xdv);

    float amv = (aAv < 0.0f) ? aAv + TWOPI_F : aAv;
    float bmv = bAv;
    float gmv = (cCv < 0.0f) ? cCv + TWOPI_F : cCv;

    float sa1, ca1, sb1, cb1, sg1, cg1;
    fast_sincos(amv, sa1, ca1);
    fast_sincos(bmv, sb1, cb1);
    fast_sincos(gmv, sg1, cg1);

    float cg2 = cg1*cg1 - sg1*sg1, sg2 = 2.f*sg1*cg1;
    float cg4 = cg2*cg2 - sg2*sg2, sg4 = 2.f*sg2*cg2;

    constexpr int P4p[5] = {1,3,4,6,8};
    constexpr int P4m[4] = {0,2,5,7};
    constexpr int P6p[7] = {1,3,5,6,8,10,12};
    constexpr int P6m[6] = {0,2,4,7,9,11};

    float loss;
    {   // l = 4
        float u4v[9];
        const float hi = 0.6455f, ce = 0.7638f;
        float t0v = sg4*hi, t8v = cg4*hi;
#pragma unroll
        for (int a = 0; a < 4; ++a) {
            const int r = P4m[a];
            u4v[r] = J4g[r*9+0] * t0v;
        }
#pragma unroll
        for (int a = 0; a < 5; ++a) {
            const int r = P4p[a];
            u4v[r] = fmaf(J4g[r*9+4], ce, J4g[r*9+8]*t8v);
        }
        roty_val<4>(u4v, cb1, sb1);
        float p4v[9];
        matvec_list_val<9,4>(P4m, u4v, p4v, J4g);
        matvec_list_val<9,5>(P4p, u4v, p4v, J4g);
        roty_val<4>(p4v, ca1, sa1);
        float s4s = 0.f;
#pragma unroll
        for (int i = 0; i < 9; ++i) {
            float d = p4v[i] - tgt4[i];
            s4s = fmaf(d, d, s4s);
        }
        loss = s4s / 9.0f;
    }
    {   // l = 6
        float u6v[13];
        const float hi = -0.9354f, ce = 0.3536f;
        float t2v = sg4*hi, t10v = cg4*hi;
#pragma unroll
        for (int a = 0; a < 6; ++a) {
            const int r = P6m[a];
            u6v[r] = J6g[r*13+2] * t2v;
        }
#pragma unroll
        for (int a = 0; a < 7; ++a) {
            const int r = P6p[a];
            u6v[r] = fmaf(J6g[r*13+6], ce, J6g[r*13+10]*t10v);
        }
        roty_val<6>(u6v, cb1, sb1);
        float p6v[13];
        matvec_list_val<13,6>(P6m, u6v, p6v, J6g);
        matvec_list_val<13,7>(P6p, u6v, p6v, J6g);
        roty_val<6>(p6v, ca1, sa1);
        float s6s = 0.f;
#pragma unroll
        for (int i = 0; i < 13; ++i) {
            float d = p6v[i] - tgt6[i];
            s6s = fmaf(d, d, s6s);
        }
        loss += 0.5f * (s6s / 13.0f);
    }
    loss_out = loss;
}

// ---------------------------------------------------------------------------
// Setup kernel: J_l = expm((pi/sqrt2)(X0r + X1r)) in fp64 (scaling&squaring).
// block 0 -> l=4 (ws[0..80]), block 1 -> l=6 (ws[81..249]).
// ---------------------------------------------------------------------------
__global__ void setup_J_kernel(float* __restrict__ Jout) {
    const int l  = (blockIdx.x == 0) ? 4 : 6;
    const int n  = 2 * l + 1;
    const int nn = n * n;
    const int tid = threadIdx.x;

    __shared__ double Qre[169], Qim[169], A[169], E[169], T[169], Wm[169];

    for (int i = tid; i < nn; i += blockDim.x) { Qre[i] = 0.0; Qim[i] = 0.0; }
    __syncthreads();

    if (tid < n) {
        int i = tid, m = i - l;
        double inv = 0.70710678118654752440;
        if (m < 0) {
            Qre[i*n + (2*l - i)] = inv;
            Qim[i*n + i]         = -inv;
        } else if (m == 0) {
            Qre[i*n + l] = 1.0;
        } else {
            double sgn = (m & 1) ? -1.0 : 1.0;
            Qre[i*n + i]         = sgn * inv;
            Qim[i*n + (2*l - i)] = sgn * inv;
        }
    }
    __syncthreads();

    if (tid < nn) {
        int r = tid / n, c = tid % n;
        double jj = (double)(l * (l + 1));
        double ar = 0.0, ai = 0.0;
        if (r > 0) {
            double md = (double)(r - 1 - l);
            double sub = -0.5 * sqrt(jj - md * (md + 1.0));
            ar += sub * Qre[(r-1)*n + c]; ai += sub * Qim[(r-1)*n + c];
        }
        if (r < n - 1) {
            double md = (double)(r - l);
            double sup = 0.5 * sqrt(jj - md * (md + 1.0));
            ar += sup * Qre[(r+1)*n + c]; ai += sup * Qim[(r+1)*n + c];
        }
        E[tid] = ar; T[tid] = ai;
    }
    __syncthreads();

    if (tid < nn) {
        int r = tid / n, c = tid % n;
        double s = 0.0;
        for (int i = 0; i < n; ++i)
            s += Qre[i*n + r] * E[i*n + c] + Qim[i*n + r] * T[i*n + c];
        Wm[tid] = s;
    }
    __syncthreads();

    if (tid < nn) {
        int r = tid / n, c = tid % n;
        double x1 = ((r + c) == 2*l && r != c) ? (double)(c - l) : 0.0;
        A[tid] = 2.2214414690791831235 * (Wm[tid] + x1) * (1.0 / 256.0);
    }
    __syncthreads();

    if (tid < nn) {
        int r = tid / n, c = tid % n;
        double idv = (r == c) ? 1.0 : 0.0;
        E[tid] = idv; T[tid] = idv;
    }
    __syncthreads();

    for (int k = 1; k <= 16; ++k) {
        double val = 0.0;
        if (tid < nn) {
            int r = tid / n, c = tid % n;
            for (int i = 0; i < n; ++i) val += T[r*n + i] * A[i*n + c];
            val /= (double)k;
        }
        __syncthreads();
        if (tid < nn) { T[tid] = val; E[tid] += val; }
        __syncthreads();
    }

    for (int s = 0; s < 8; ++s) {
        double val = 0.0;
        if (tid < nn) {
            int r = tid / n, c = tid % n;
            for (int i = 0; i < n; ++i) val += E[r*n + i] * E[i*n + c];
        }
        __syncthreads();
        if (tid < nn) Wm[tid] = val;
        __syncthreads();
        if (tid < nn) E[tid] = Wm[tid];
        __syncthreads();
    }

    if (tid < nn) Jout[(l == 4 ? 0 : 81) + tid] = (float)E[tid];
}

// ---------------------------------------------------------------------------
// Main kernel: 192 threads = 48 instances (4 lanes each) = 8 batch elements.
// ---------------------------------------------------------------------------
__global__ __launch_bounds__(192) void opt_kernel(
    const float* __restrict__ f4, const float* __restrict__ f6,
    const float* __restrict__ qr, const float* __restrict__ Jg,
    float* __restrict__ out)
{
    __shared__ float tg4[8 * 9], tg6[8 * 13];
    __shared__ float selL[48], selQ[48 * 4];

    const int tid = threadIdx.x;
    for (int i = tid; i < 72;  i += 192) tg4[i] = f4[blockIdx.x * 72  + i];
    for (int i = tid; i < 104; i += 192) tg6[i] = f6[blockIdx.x * 104 + i];
    __syncthreads();

    const float* __restrict__ J4g = Jg;        // 81 floats
    const float* __restrict__ J6g = Jg + 81;   // 169 floats

    const int inst = tid >> 2;          // 0..47
    const int lane = tid & 3;           // tangent seed / Adam component
    const int gi   = blockIdx.x * 48 + inst;
    const int e    = gi / 6;
    const int k    = gi % 6;
    const int eloc = inst / 6;          // 0..7
    const float* tgt4 = &tg4[eloc * 9];
    const float* tgt6 = &tg6[eloc * 13];

    // ---- init u = fix_sign(normalize(concat(first, normalize(q_rand)))) ----
    float u0, u1, u2, u3;
    {
        float t0, t1, t2, t3;
        if (k == 0) {
            t0 = 1.0f; t1 = 0.0f; t2 = 0.0f; t3 = 0.0f;
        } else {
            const float* rp = &qr[(e * 5 + (k - 1)) * 4];
            normalize4(rp[0], rp[1], rp[2], rp[3], t0, t1, t2, t3);
        }
        normalize4(t0, t1, t2, t3, u0, u1, u2, u3);
        fixsign4(u0, u1, u2, u3);
    }

    float mAd = 0.0f, vAd = 0.0f;
    float b1p = 1.0f, b2p = 1.0f;
    const int base = tid & 60;          // lane-quad base within the 64-wide wave

#pragma unroll 1
    for (int step = 0; step < 25; ++step) {
        float dl = eval_grad(u0, u1, u2, u3, lane, J4g, J6g, tgt4, tgt6);
        float g = dl * (1.0f / 49152.0f);   // jnp.mean over bsz*k instances
        b1p *= 0.9f; b2p *= 0.999f;
        mAd = 0.9f   * mAd + 0.1f   * g;
        vAd = 0.999f * vAd + 0.001f * g * g;
        float mh = mAd / (1.0f - b1p);
        float vh = vAd / (1.0f - b2p);
        float comp = (lane == 0) ? u0 : (lane == 1) ? u1 : (lane == 2) ? u2 : u3;
        float un = comp - 0.08f * mh / (sqrtf(vh) + 1e-8f);
        u0 = __shfl(un, base + 0, 64);
        u1 = __shfl(un, base + 1, 64);
        u2 = __shfl(un, base + 2, 64);
        u3 = __shfl(un, base + 3, 64);
    }

    float lossF, qf0, qf1, qf2, qf3;
    eval_final(u0, u1, u2, u3, J4g, J6g, tgt4, tgt6, lossF, qf0, qf1, qf2, qf3);

    if (lane == 0) {
        selL[inst] = lossF;
        selQ[inst * 4 + 0] = qf0; selQ[inst * 4 + 1] = qf1;
        selQ[inst * 4 + 2] = qf2; selQ[inst * 4 + 3] = qf3;
    }
    __syncthreads();

    // ---- per-element argmin over 6 starts + final fix_sign(normalize()) ----
    if (tid < 8) {
        int b0 = tid * 6, best = 0;
        float bl = selL[b0];
#pragma unroll
        for (int kk = 1; kk < 6; ++kk) {
            float v = selL[b0 + kk];
            if (v < bl) { bl = v; best = kk; }
        }
        float o0, o1, o2, o3;
        normalize4(selQ[(b0 + best) * 4 + 0], selQ[(b0 + best) * 4 + 1],
                   selQ[(b0 + best) * 4 + 2], selQ[(b0 + best) * 4 + 3],
                   o0, o1, o2, o3);
        fixsign4(o0, o1, o2, o3);
        int eo = blockIdx.x * 8 + tid;
        out[eo * 4 + 0] = o0; out[eo * 4 + 1] = o1;
        out[eo * 4 + 2] = o2; out[eo * 4 + 3] = o3;
    }
}

extern "C" void kernel_launch(void* const* d_in, const int* in_sizes, int n_in,
                              void* d_out, int out_size, void* d_ws, size_t ws_size,
                              hipStream_t stream) {
    const float* f4 = (const float*)d_in[0];   // (8192, 9)
    const float* f6 = (const float*)d_in[1];   // (8192, 13)
    const float* qr = (const float*)d_in[2];   // (8192, 5, 4)
    float* out = (float*)d_out;                // (8192, 4)
    float* Jws = (float*)d_ws;                 // 250 floats: J4 (81) + J6 (169)

    setup_J_kernel<<<2, 256, 0, stream>>>(Jws);
    opt_kernel<<<1024, 192, 0, stream>>>(f4, f6, qr, Jws, out);
}

// Round 7
// 261.858 us; speedup vs baseline: 18.8392x; 1.2424x over previous
//
#include <hip/hip_runtime.h>
#include <math.h>

// ---------------------------------------------------------------------------
// InvariantSRModel: 8192 x 6 restarts x 25 Adam steps fitting a quaternion so
// that Wigner-D(l=4,6) applied to fixed templates S4/S6 matches random targets.
//
// D(a,b,c) = RotY(a) J RotY(b) J RotY(g) applied to sparse S (mat-vec only).
// J = exp((pi/sqrt2)(X0+X1)), fp64 scaling&squaring on device each launch.
// J is block-diagonal under the z->-z mirror parity s(m) = (-1)^m (m>=0),
// (-1)^(|m|+1) (m<0):  l=4: {1,3,4,6,8}|{0,2,5,7},
//                      l=6: {1,3,5,6,8,10,12}|{0,2,4,7,9,11}.
//
// ROUND 7: Cartesian trig. The gradient path never needs the Euler angles --
// only their sines/cosines and tangents:
//   alpha: sin=v0/h, cos=v2/h (h=hypot(v0,v2));  beta: cos=v1, sin=sqrt(1-v1^2)
//   gamma: sin=yn/hg, cos=xd/hg.
// This removes 2x atan2f, 1x acosf, 4x sincos, and all mod-2pi fixups from
// eval_grad (~21% of its ops). Pole semantics preserved: -0*inf=NaN,
// -x*inf=+-inf match the reference's -0/0, -x/0 (dead-instance paths).
// eval_final keeps the exact libm/ref-shaped path (runs once).
//
// Gradient: forward-mode duals, 4 lanes per instance (one tangent seed each).
// Lessons kept: no waves-per-EU floor (RA spills chasing it), scalar ABIs,
// no runtime-indexed locals, value-only final eval (fix_sign loss-invariant),
// J read from global with wave-uniform constant indices (scalarizes).
// ---------------------------------------------------------------------------

#define TWOPI_F 6.283185307179586f
#define EPS_Q   1e-12f

__device__ __forceinline__ bool finitef(float x) {
    return ((__float_as_uint(x) & 0x7f800000u) != 0x7f800000u);
}

// sincos valid for |x| <= ~16 (we use |x| <= 2pi). NaN in -> NaN out.
// (used only in eval_final now)
__device__ __forceinline__ void fast_sincos(float x, float& s, float& c) {
    float fk = rintf(x * 0.6366197723675814f);   // x * 2/pi
    int   q  = (int)fk;
    float r  = fmaf(-fk, 1.5703125f, x);
    r = fmaf(-fk, 4.837512969970703125e-4f, r);
    r = fmaf(-fk, 7.549789948768648e-8f, r);
    float z  = r * r;
    float sp = fmaf(fmaf(fmaf(-1.9515295891e-4f, z, 8.3321608736e-3f), z,
                         -1.6666654611e-1f), z * r, r);
    float cp = fmaf(fmaf(fmaf(2.443315711809948e-5f, z, -1.388731625493765e-3f), z,
                         4.166664568298827e-2f), z * z, fmaf(-0.5f, z, 1.0f));
    int qa = q & 3;
    float s0 = (qa & 1) ? cp : sp;
    float c0 = (qa & 1) ? sp : cp;
    if (qa == 1 || qa == 2) c0 = -c0;
    if (qa >= 2)            s0 = -s0;
    s = s0; c = c0;
}

// _normalize_quat value-only, scalar ABI (isfinite -> 0, norm<EPS -> unit)
__device__ __forceinline__ void normalize4(float i0, float i1, float i2, float i3,
                                           float& o0, float& o1, float& o2, float& o3) {
    float a0 = finitef(i0) ? i0 : 0.0f;
    float a1 = finitef(i1) ? i1 : 0.0f;
    float a2 = finitef(i2) ? i2 : 0.0f;
    float a3 = finitef(i3) ? i3 : 0.0f;
    float n = sqrtf(a0*a0 + a1*a1 + a2*a2 + a3*a3);
    if (n < EPS_Q) { o0 = 1.0f; o1 = 0.0f; o2 = 0.0f; o3 = 0.0f; }
    else {
        float mx = fmaxf(n, EPS_Q);
        o0 = a0 / mx; o1 = a1 / mx; o2 = a2 / mx; o3 = a3 / mx;
    }
}

__device__ __forceinline__ void fixsign4(float& q0, float& q1, float& q2, float& q3) {
    if (q0 < 0.0f) { q0 = -q0; q1 = -q1; q2 = -q2; q3 = -q3; }
}

// ---- RotY block rotations with running angle-addition recurrence ----
template <int L>
__device__ __forceinline__ void roty_grad(float* v, float* d, float c1, float s1, float thd) {
    float cm = c1, sm = s1;
#pragma unroll
    for (int m = 1; m <= L; ++m) {
        float fm = (float)m;
        float cd = -fm * sm * thd;
        float sd =  fm * cm * thd;
        float lov = v[L-m], lod = d[L-m], hiv = v[L+m], hid = d[L+m];
        v[L-m] = cm*lov + sm*hiv;
        d[L-m] = cm*lod + cd*lov + sm*hid + sd*hiv;
        v[L+m] = cm*hiv - sm*lov;
        d[L+m] = cm*hid + cd*hiv - sm*lod - sd*lov;
        if (m < L) {
            float cn = cm*c1 - sm*s1;
            float sn = sm*c1 + cm*s1;
            cm = cn; sm = sn;
        }
    }
}

template <int L>
__device__ __forceinline__ void roty_val(float* v, float c1, float s1) {
    float cm = c1, sm = s1;
#pragma unroll
    for (int m = 1; m <= L; ++m) {
        float lov = v[L-m], hiv = v[L+m];
        v[L-m] = cm*lov + sm*hiv;
        v[L+m] = cm*hiv - sm*lov;
        if (m < L) {
            float cn = cm*c1 - sm*s1;
            float sn = sm*c1 + cm*s1;
            cm = cn; sm = sn;
        }
    }
}

// Block-diagonal J matvec over an index LIST (compile-time), grad version.
template <int N, int K>
__device__ __forceinline__ void matvec_list_grad(const int (&idx)[K],
                                                 const float* v, const float* d,
                                                 float* ov, float* od,
                                                 const float* __restrict__ Jm) {
#pragma unroll
    for (int a = 0; a < K; ++a) {
        const int r = idx[a];
        float sv = 0.0f, sd = 0.0f;
#pragma unroll
        for (int b = 0; b < K; ++b) {
            const int c = idx[b];
            float jv = Jm[r*N + c];
            sv = fmaf(jv, v[c], sv);
            sd = fmaf(jv, d[c], sd);
        }
        ov[r] = sv; od[r] = sd;
    }
}

template <int N, int K>
__device__ __forceinline__ void matvec_list_val(const int (&idx)[K],
                                                const float* v, float* ov,
                                                const float* __restrict__ Jm) {
#pragma unroll
    for (int a = 0; a < K; ++a) {
        const int r = idx[a];
        float sv = 0.0f;
#pragma unroll
        for (int b = 0; b < K; ++b) {
            const int c = idx[b];
            sv = fmaf(Jm[r*N + c], v[c], sv);
        }
        ov[r] = sv;
    }
}

// ---------------------------------------------------------------------------
// eval_grad: directional derivative of the loss wrt u[seed]. No loss value,
// no q output, no fix_sign (R(q) quadratic in q: sign flip cancels).
// Cartesian trig: no atan2/acos/sincos anywhere.
// ---------------------------------------------------------------------------
__device__ __forceinline__ float eval_grad(
    float uu0, float uu1, float uu2, float uu3, int seed,
    const float* __restrict__ J4g, const float* __restrict__ J6g,
    const float* __restrict__ tgt4, const float* __restrict__ tgt6)
{
    // ---- q = normalize(u) with tangent ----
    bool f0 = finitef(uu0), f1 = finitef(uu1), f2 = finitef(uu2), f3 = finitef(uu3);
    float w0 = f0 ? uu0 : 0.0f, w1 = f1 ? uu1 : 0.0f;
    float w2 = f2 ? uu2 : 0.0f, w3 = f3 ? uu3 : 0.0f;
    float wd0 = (f0 && seed == 0) ? 1.0f : 0.0f;
    float wd1 = (f1 && seed == 1) ? 1.0f : 0.0f;
    float wd2 = (f2 && seed == 2) ? 1.0f : 0.0f;
    float wd3 = (f3 && seed == 3) ? 1.0f : 0.0f;
    float ss = w0*w0 + w1*w1 + w2*w2 + w3*w3;
    float n  = sqrtf(ss);
    float q0v, q1v, q2v, q3v, q0d, q1d, q2d, q3d;
    if (n < EPS_Q) {
        q0v = 1.f; q1v = 0.f; q2v = 0.f; q3v = 0.f;
        q0d = 0.f; q1d = 0.f; q2d = 0.f; q3d = 0.f;
    } else {
        float nd  = (w0*wd0 + w1*wd1 + w2*wd2 + w3*wd3) / n;
        float rmx = 1.0f / fmaxf(n, EPS_Q);
        float s   = nd * rmx;
        q0v = w0 * rmx; q0d = rmx * fmaf(-w0, s, wd0);
        q1v = w1 * rmx; q1d = rmx * fmaf(-w1, s, wd1);
        q2v = w2 * rmx; q2d = rmx * fmaf(-w2, s, wd2);
        q3v = w3 * rmx; q3d = rmx * fmaf(-w3, s, wd3);
    }

    // ---- the 7 rotation-matrix entries we need, with tangents ----
    float R00v = 1.f - 2.f*(q2v*q2v + q3v*q3v);
    float R00d = -4.f*(q2v*q2d + q3v*q3d);
    float R01v = 2.f*(q1v*q2v - q0v*q3v);
    float R01d = 2.f*(q1v*q2d + q1d*q2v - q0v*q3d - q0d*q3v);
    float R02v = 2.f*(q1v*q3v + q0v*q2v);
    float R02d = 2.f*(q1v*q3d + q1d*q3v + q0v*q2d + q0d*q2v);
    float R11v = 1.f - 2.f*(q1v*q1v + q3v*q3v);
    float R11d = -4.f*(q1v*q1d + q3v*q3d);
    float R21v = 2.f*(q2v*q3v + q0v*q1v);
    float R21d = 2.f*(q2v*q3d + q2d*q3v + q0v*q1d + q0d*q1v);
    float R20v = 2.f*(q1v*q3v - q0v*q2v);
    float R20d = 2.f*(q1v*q3d + q1d*q3v - q0v*q2d - q0d*q2v);
    float R22v = 1.f - 2.f*(q1v*q1v + q2v*q2v);
    float R22d = -4.f*(q1v*q1d + q2v*q2d);

    // ---- column normalize + clip (lax balanced-eq tie rule on tangent) ----
    float ss2 = R01v*R01v + R11v*R11v + R21v*R21v;
    float n2  = sqrtf(ss2);
    float n2d = (R01v*R01d + R11v*R11d + R21v*R21d) / n2;
    float mx2 = fmaxf(n2, 1e-12f);
    float rm2 = 1.0f / mx2;
    float s2  = ((n2 > 1e-12f) ? n2d : 0.0f) * rm2;
    float v0v = R01v * rm2, v0d = rm2 * fmaf(-R01v, s2, R01d);
    float v1v = R11v * rm2, v1d = rm2 * fmaf(-R11v, s2, R11d);
    float v2v = R21v * rm2, v2d = rm2 * fmaf(-R21v, s2, R21d);
    {
        float tv, td;
        tv = v0v; td = v0d;
        td = (tv > -1.0f) ? td : ((tv == -1.0f) ? 0.5f*td : 0.0f);
        tv = (tv > -1.0f) ? tv : -1.0f;
        td = (tv <  1.0f) ? td : ((tv ==  1.0f) ? 0.5f*td : 0.0f);
        tv = (tv <  1.0f) ? tv :  1.0f;
        v0v = tv; v0d = td;
        tv = v1v; td = v1d;
        td = (tv > -1.0f) ? td : ((tv == -1.0f) ? 0.5f*td : 0.0f);
        tv = (tv > -1.0f) ? tv : -1.0f;
        td = (tv <  1.0f) ? td : ((tv ==  1.0f) ? 0.5f*td : 0.0f);
        tv = (tv <  1.0f) ? tv :  1.0f;
        v1v = tv; v1d = td;
        tv = v2v; td = v2d;
        td = (tv > -1.0f) ? td : ((tv == -1.0f) ? 0.5f*td : 0.0f);
        tv = (tv > -1.0f) ? tv : -1.0f;
        td = (tv <  1.0f) ? td : ((tv ==  1.0f) ? 0.5f*td : 0.0f);
        tv = (tv <  1.0f) ? tv :  1.0f;
        v2v = tv; v2d = td;
    }

    // ---- Cartesian trig (no angles ever materialized) ----
    // alpha = atan2(v0, v2): sin = v0/h, cos = v2/h
    float h2a = v0v*v0v + v2v*v2v;
    float rha = rsqrtf(h2a);
    float sa1 = v0v * rha, ca1 = v2v * rha;
    float amd = (v2v*v0d - v0v*v2d) * (rha * rha);   // NaN/inf at pole = ref
    // beta = acos(v1): cos = v1, sin = sqrt(1-v1^2)
    float omv = 1.0f - v1v*v1v;
    float cb1 = v1v;
    float sb1 = sqrtf(omv);
    float bmd = -v1d * rsqrtf(omv);                  // -0*inf=NaN, -x*inf=+-inf = ref
    // gamma = atan2(yn, xd): sin = yn/hg, cos = xd/hg
    float cad = -sa1*amd, sad = ca1*amd;
    float ynv = ca1*R02v - sa1*R22v;
    float ynd = ca1*R02d + cad*R02v - sa1*R22d - sad*R22v;
    float xdv = ca1*R00v - sa1*R20v;
    float xdd = ca1*R00d + cad*R00v - sa1*R20d - sad*R20v;
    float h2g = ynv*ynv + xdv*xdv;
    float rhg = rsqrtf(h2g);
    float sg1 = ynv * rhg, cg1 = xdv * rhg;
    float gmd = (xdv*ynd - ynv*xdd) * (rhg * rhg);

    // ---- gamma stage: sparse S -> only the m=4 pair rotates ----
    float cg2 = cg1*cg1 - sg1*sg1, sg2 = 2.f*sg1*cg1;
    float cg4 = cg2*cg2 - sg2*sg2, sg4 = 2.f*sg2*cg2;
    float c4d = -4.f*sg4*gmd, s4d = 4.f*cg4*gmd;

    constexpr int P4p[5] = {1,3,4,6,8};
    constexpr int P4m[4] = {0,2,5,7};
    constexpr int P6p[7] = {1,3,5,6,8,10,12};
    constexpr int P6m[6] = {0,2,4,7,9,11};

    float dl;
    {   // ================= l = 4 chain =================
        float u4v[9], u4d[9];
        const float hi = 0.6455f, ce = 0.7638f;
        float t0v = sg4*hi, t0d = s4d*hi;
        float t8v = cg4*hi, t8d = c4d*hi;
#pragma unroll
        for (int a = 0; a < 4; ++a) {
            const int r = P4m[a];
            float j0 = J4g[r*9+0];
            u4v[r] = j0 * t0v;
            u4d[r] = j0 * t0d;
        }
#pragma unroll
        for (int a = 0; a < 5; ++a) {
            const int r = P4p[a];
            float j4 = J4g[r*9+4], j8 = J4g[r*9+8];
            u4v[r] = fmaf(j4, ce, j8*t8v);
            u4d[r] = j8 * t8d;
        }
        roty_grad<4>(u4v, u4d, cb1, sb1, bmd);
        float p4v[9], p4d[9];
        matvec_list_grad<9,4>(P4m, u4v, u4d, p4v, p4d, J4g);
        matvec_list_grad<9,5>(P4p, u4v, u4d, p4v, p4d, J4g);
        roty_grad<4>(p4v, p4d, ca1, sa1, amd);
        float g4s = 0.f;
#pragma unroll
        for (int i = 0; i < 9; ++i) {
            float d = p4v[i] - tgt4[i];
            g4s = fmaf(d, p4d[i], g4s);
        }
        dl = 2.0f * g4s / 9.0f;
    }
    {   // ================= l = 6 chain =================
        float u6v[13], u6d[13];
        const float hi = -0.9354f, ce = 0.3536f;
        float t2v = sg4*hi,  t2d = s4d*hi;
        float t10v = cg4*hi, t10d = c4d*hi;
#pragma unroll
        for (int a = 0; a < 6; ++a) {
            const int r = P6m[a];
            float j2 = J6g[r*13+2];
            u6v[r] = j2 * t2v;
            u6d[r] = j2 * t2d;
        }
#pragma unroll
        for (int a = 0; a < 7; ++a) {
            const int r = P6p[a];
            float j6 = J6g[r*13+6], j10 = J6g[r*13+10];
            u6v[r] = fmaf(j6, ce, j10*t10v);
            u6d[r] = j10 * t10d;
        }
        roty_grad<6>(u6v, u6d, cb1, sb1, bmd);
        float p6v[13], p6d[13];
        matvec_list_grad<13,6>(P6m, u6v, u6d, p6v, p6d, J6g);
        matvec_list_grad<13,7>(P6p, u6v, u6d, p6v, p6d, J6g);
        roty_grad<6>(p6v, p6d, ca1, sa1, amd);
        float g6s = 0.f;
#pragma unroll
        for (int i = 0; i < 13; ++i) {
            float d = p6v[i] - tgt6[i];
            g6s = fmaf(d, p6d[i], g6s);
        }
        dl += g6s / 13.0f;     // 0.5 * 2/13
    }
    return dl;
}

// ---------------------------------------------------------------------------
// eval_final: VALUE ONLY -- loss and q = fix_sign(normalize(u)).
// Keeps the libm/ref-shaped path (runs once; argmin stability).
// ---------------------------------------------------------------------------
__device__ __forceinline__ void eval_final(
    float uu0, float uu1, float uu2, float uu3,
    const float* __restrict__ J4g, const float* __restrict__ J6g,
    const float* __restrict__ tgt4, const float* __restrict__ tgt6,
    float& loss_out, float& q0o, float& q1o, float& q2o, float& q3o)
{
    float q0v, q1v, q2v, q3v;
    normalize4(uu0, uu1, uu2, uu3, q0v, q1v, q2v, q3v);
    fixsign4(q0v, q1v, q2v, q3v);
    q0o = q0v; q1o = q1v; q2o = q2v; q3o = q3v;

    float R00v = 1.f - 2.f*(q2v*q2v + q3v*q3v);
    float R01v = 2.f*(q1v*q2v - q0v*q3v);
    float R02v = 2.f*(q1v*q3v + q0v*q2v);
    float R11v = 1.f - 2.f*(q1v*q1v + q3v*q3v);
    float R21v = 2.f*(q2v*q3v + q0v*q1v);
    float R20v = 2.f*(q1v*q3v - q0v*q2v);
    float R22v = 1.f - 2.f*(q1v*q1v + q2v*q2v);

    float n2  = sqrtf(R01v*R01v + R11v*R11v + R21v*R21v);
    float mx2 = fmaxf(n2, 1e-12f);
    float v0v = fminf(fmaxf(R01v / mx2, -1.0f), 1.0f);
    float v1v = fminf(fmaxf(R11v / mx2, -1.0f), 1.0f);
    float v2v = fminf(fmaxf(R21v / mx2, -1.0f), 1.0f);

    float bAv = acosf(v1v);
    float aAv = atan2f(v0v, v2v);
    float sav, cav;
    fast_sincos(aAv, sav, cav);
    float ynv = cav*R02v - sav*R22v;
    float xdv = cav*R00v - sav*R20v;
    float cCv = atan2f(ynv, xdv);

    float amv = (aAv < 0.0f) ? aAv + TWOPI_F : aAv;
    float bmv = bAv;
    float gmv = (cCv < 0.0f) ? cCv + TWOPI_F : cCv;

    float sa1, ca1, sb1, cb1, sg1, cg1;
    fast_sincos(amv, sa1, ca1);
    fast_sincos(bmv, sb1, cb1);
    fast_sincos(gmv, sg1, cg1);

    float cg2 = cg1*cg1 - sg1*sg1, sg2 = 2.f*sg1*cg1;
    float cg4 = cg2*cg2 - sg2*sg2, sg4 = 2.f*sg2*cg2;

    constexpr int P4p[5] = {1,3,4,6,8};
    constexpr int P4m[4] = {0,2,5,7};
    constexpr int P6p[7] = {1,3,5,6,8,10,12};
    constexpr int P6m[6] = {0,2,4,7,9,11};

    float loss;
    {   // l = 4
        float u4v[9];
        const float hi = 0.6455f, ce = 0.7638f;
        float t0v = sg4*hi, t8v = cg4*hi;
#pragma unroll
        for (int a = 0; a < 4; ++a) {
            const int r = P4m[a];
            u4v[r] = J4g[r*9+0] * t0v;
        }
#pragma unroll
        for (int a = 0; a < 5; ++a) {
            const int r = P4p[a];
            u4v[r] = fmaf(J4g[r*9+4], ce, J4g[r*9+8]*t8v);
        }
        roty_val<4>(u4v, cb1, sb1);
        float p4v[9];
        matvec_list_val<9,4>(P4m, u4v, p4v, J4g);
        matvec_list_val<9,5>(P4p, u4v, p4v, J4g);
        roty_val<4>(p4v, ca1, sa1);
        float s4s = 0.f;
#pragma unroll
        for (int i = 0; i < 9; ++i) {
            float d = p4v[i] - tgt4[i];
            s4s = fmaf(d, d, s4s);
        }
        loss = s4s / 9.0f;
    }
    {   // l = 6
        float u6v[13];
        const float hi = -0.9354f, ce = 0.3536f;
        float t2v = sg4*hi, t10v = cg4*hi;
#pragma unroll
        for (int a = 0; a < 6; ++a) {
            const int r = P6m[a];
            u6v[r] = J6g[r*13+2] * t2v;
        }
#pragma unroll
        for (int a = 0; a < 7; ++a) {
            const int r = P6p[a];
            u6v[r] = fmaf(J6g[r*13+6], ce, J6g[r*13+10]*t10v);
        }
        roty_val<6>(u6v, cb1, sb1);
        float p6v[13];
        matvec_list_val<13,6>(P6m, u6v, p6v, J6g);
        matvec_list_val<13,7>(P6p, u6v, p6v, J6g);
        roty_val<6>(p6v, ca1, sa1);
        float s6s = 0.f;
#pragma unroll
        for (int i = 0; i < 13; ++i) {
            float d = p6v[i] - tgt6[i];
            s6s = fmaf(d, d, s6s);
        }
        loss += 0.5f * (s6s / 13.0f);
    }
    loss_out = loss;
}

// ---------------------------------------------------------------------------
// Setup kernel: J_l = expm((pi/sqrt2)(X0r + X1r)) in fp64 (scaling&squaring).
// block 0 -> l=4 (ws[0..80]), block 1 -> l=6 (ws[81..249]).
// ---------------------------------------------------------------------------
__global__ void setup_J_kernel(float* __restrict__ Jout) {
    const int l  = (blockIdx.x == 0) ? 4 : 6;
    const int n  = 2 * l + 1;
    const int nn = n * n;
    const int tid = threadIdx.x;

    __shared__ double Qre[169], Qim[169], A[169], E[169], T[169], Wm[169];

    for (int i = tid; i < nn; i += blockDim.x) { Qre[i] = 0.0; Qim[i] = 0.0; }
    __syncthreads();

    if (tid < n) {
        int i = tid, m = i - l;
        double inv = 0.70710678118654752440;
        if (m < 0) {
            Qre[i*n + (2*l - i)] = inv;
            Qim[i*n + i]         = -inv;
        } else if (m == 0) {
            Qre[i*n + l] = 1.0;
        } else {
            double sgn = (m & 1) ? -1.0 : 1.0;
            Qre[i*n + i]         = sgn * inv;
            Qim[i*n + (2*l - i)] = sgn * inv;
        }
    }
    __syncthreads();

    if (tid < nn) {
        int r = tid / n, c = tid % n;
        double jj = (double)(l * (l + 1));
        double ar = 0.0, ai = 0.0;
        if (r > 0) {
            double md = (double)(r - 1 - l);
            double sub = -0.5 * sqrt(jj - md * (md + 1.0));
            ar += sub * Qre[(r-1)*n + c]; ai += sub * Qim[(r-1)*n + c];
        }
        if (r < n - 1) {
            double md = (double)(r - l);
            double sup = 0.5 * sqrt(jj - md * (md + 1.0));
            ar += sup * Qre[(r+1)*n + c]; ai += sup * Qim[(r+1)*n + c];
        }
        E[tid] = ar; T[tid] = ai;
    }
    __syncthreads();

    if (tid < nn) {
        int r = tid / n, c = tid % n;
        double s = 0.0;
        for (int i = 0; i < n; ++i)
            s += Qre[i*n + r] * E[i*n + c] + Qim[i*n + r] * T[i*n + c];
        Wm[tid] = s;
    }
    __syncthreads();

    if (tid < nn) {
        int r = tid / n, c = tid % n;
        double x1 = ((r + c) == 2*l && r != c) ? (double)(c - l) : 0.0;
        A[tid] = 2.2214414690791831235 * (Wm[tid] + x1) * (1.0 / 256.0);
    }
    __syncthreads();

    if (tid < nn) {
        int r = tid / n, c = tid % n;
        double idv = (r == c) ? 1.0 : 0.0;
        E[tid] = idv; T[tid] = idv;
    }
    __syncthreads();

    for (int k = 1; k <= 16; ++k) {
        double val = 0.0;
        if (tid < nn) {
            int r = tid / n, c = tid % n;
            for (int i = 0; i < n; ++i) val += T[r*n + i] * A[i*n + c];
            val /= (double)k;
        }
        __syncthreads();
        if (tid < nn) { T[tid] = val; E[tid] += val; }
        __syncthreads();
    }

    for (int s = 0; s < 8; ++s) {
        double val = 0.0;
        if (tid < nn) {
            int r = tid / n, c = tid % n;
            for (int i = 0; i < n; ++i) val += E[r*n + i] * E[i*n + c];
        }
        __syncthreads();
        if (tid < nn) Wm[tid] = val;
        __syncthreads();
        if (tid < nn) E[tid] = Wm[tid];
        __syncthreads();
    }

    if (tid < nn) Jout[(l == 4 ? 0 : 81) + tid] = (float)E[tid];
}

// ---------------------------------------------------------------------------
// Main kernel: 192 threads = 48 instances (4 lanes each) = 8 batch elements.
// ---------------------------------------------------------------------------
__global__ __launch_bounds__(192) void opt_kernel(
    const float* __restrict__ f4, const float* __restrict__ f6,
    const float* __restrict__ qr, const float* __restrict__ Jg,
    float* __restrict__ out)
{
    __shared__ float tg4[8 * 9], tg6[8 * 13];
    __shared__ float selL[48], selQ[48 * 4];

    const int tid = threadIdx.x;
    for (int i = tid; i < 72;  i += 192) tg4[i] = f4[blockIdx.x * 72  + i];
    for (int i = tid; i < 104; i += 192) tg6[i] = f6[blockIdx.x * 104 + i];
    __syncthreads();

    const float* __restrict__ J4g = Jg;        // 81 floats
    const float* __restrict__ J6g = Jg + 81;   // 169 floats

    const int inst = tid >> 2;          // 0..47
    const int lane = tid & 3;           // tangent seed / Adam component
    const int gi   = blockIdx.x * 48 + inst;
    const int e    = gi / 6;
    const int k    = gi % 6;
    const int eloc = inst / 6;          // 0..7
    const float* tgt4 = &tg4[eloc * 9];
    const float* tgt6 = &tg6[eloc * 13];

    // ---- init u = fix_sign(normalize(concat(first, normalize(q_rand)))) ----
    float u0, u1, u2, u3;
    {
        float t0, t1, t2, t3;
        if (k == 0) {
            t0 = 1.0f; t1 = 0.0f; t2 = 0.0f; t3 = 0.0f;
        } else {
            const float* rp = &qr[(e * 5 + (k - 1)) * 4];
            normalize4(rp[0], rp[1], rp[2], rp[3], t0, t1, t2, t3);
        }
        normalize4(t0, t1, t2, t3, u0, u1, u2, u3);
        fixsign4(u0, u1, u2, u3);
    }

    float mAd = 0.0f, vAd = 0.0f;
    float b1p = 1.0f, b2p = 1.0f;
    const int base = tid & 60;          // lane-quad base within the 64-wide wave

#pragma unroll 1
    for (int step = 0; step < 25; ++step) {
        float dl = eval_grad(u0, u1, u2, u3, lane, J4g, J6g, tgt4, tgt6);
        float g = dl * (1.0f / 49152.0f);   // jnp.mean over bsz*k instances
        b1p *= 0.9f; b2p *= 0.999f;
        mAd = 0.9f   * mAd + 0.1f   * g;
        vAd = 0.999f * vAd + 0.001f * g * g;
        float mh = mAd / (1.0f - b1p);
        float vh = vAd / (1.0f - b2p);
        float comp = (lane == 0) ? u0 : (lane == 1) ? u1 : (lane == 2) ? u2 : u3;
        float un = comp - 0.08f * mh / (sqrtf(vh) + 1e-8f);
        u0 = __shfl(un, base + 0, 64);
        u1 = __shfl(un, base + 1, 64);
        u2 = __shfl(un, base + 2, 64);
        u3 = __shfl(un, base + 3, 64);
    }

    float lossF, qf0, qf1, qf2, qf3;
    eval_final(u0, u1, u2, u3, J4g, J6g, tgt4, tgt6, lossF, qf0, qf1, qf2, qf3);

    if (lane == 0) {
        selL[inst] = lossF;
        selQ[inst * 4 + 0] = qf0; selQ[inst * 4 + 1] = qf1;
        selQ[inst * 4 + 2] = qf2; selQ[inst * 4 + 3] = qf3;
    }
    __syncthreads();

    // ---- per-element argmin over 6 starts + final fix_sign(normalize()) ----
    if (tid < 8) {
        int b0 = tid * 6, best = 0;
        float bl = selL[b0];
#pragma unroll
        for (int kk = 1; kk < 6; ++kk) {
            float v = selL[b0 + kk];
            if (v < bl) { bl = v; best = kk; }
        }
        float o0, o1, o2, o3;
        normalize4(selQ[(b0 + best) * 4 + 0], selQ[(b0 + best) * 4 + 1],
                   selQ[(b0 + best) * 4 + 2], selQ[(b0 + best) * 4 + 3],
                   o0, o1, o2, o3);
        fixsign4(o0, o1, o2, o3);
        int eo = blockIdx.x * 8 + tid;
        out[eo * 4 + 0] = o0; out[eo * 4 + 1] = o1;
        out[eo * 4 + 2] = o2; out[eo * 4 + 3] = o3;
    }
}

extern "C" void kernel_launch(void* const* d_in, const int* in_sizes, int n_in,
                              void* d_out, int out_size, void* d_ws, size_t ws_size,
                              hipStream_t stream) {
    const float* f4 = (const float*)d_in[0];   // (8192, 9)
    const float* f6 = (const float*)d_in[1];   // (8192, 13)
    const float* qr = (const float*)d_in[2];   // (8192, 5, 4)
    float* out = (float*)d_out;                // (8192, 4)
    float* Jws = (float*)d_ws;                 // 250 floats: J4 (81) + J6 (169)

    setup_J_kernel<<<2, 256, 0, stream>>>(Jws);
    opt_kernel<<<1024, 192, 0, stream>>>(f4, f6, qr, Jws, out);
}

// Round 8
// 195.015 us; speedup vs baseline: 25.2965x; 1.3428x over previous
//
#include <hip/hip_runtime.h>
#include <math.h>

// ---------------------------------------------------------------------------
// InvariantSRModel: 8192 x 6 restarts x 25 Adam steps fitting a quaternion so
// that Wigner-D(l=4,6) applied to fixed templates S4/S6 matches random targets.
//
// D(a,b,c) = RotY(a) J RotY(b) J RotY(g) applied to sparse S (mat-vec only).
// J = exp((pi/sqrt2)(X0+X1)) -- a FIXED matrix, now computed at COMPILE TIME
// (constexpr fp64 scaling-and-squaring expm; same algorithm that previously
// ran in the setup kernel, bit-equivalent modulo fma contraction ~1e-16).
// This removes the second dispatch (51 us of the round-7 262 us total) and
// turns all J accesses into .rodata constants.
//
// J is block-diagonal under the z->-z mirror parity s(m) = (-1)^m (m>=0),
// (-1)^(|m|+1) (m<0):  l=4: {1,3,4,6,8}|{0,2,5,7},
//                      l=6: {1,3,5,6,8,10,12}|{0,2,4,7,9,11}.
//
// Cartesian trig (round 7): gradient path needs only sin/cos of the Euler
// angles, never the angles -- no atan2/acos/sincos in the hot loop.
// Round 8: grad-path divisions/sqrts use the single-instruction approx
// builtins (rcpf/rsqf/sqrtf); 20x error headroom. eval_final keeps libm.
// Targets preloaded to registers (was 22 LDS reads per eval).
//
// Gradient: forward-mode duals, 4 lanes per instance (one tangent seed each).
// Lessons kept: no waves-per-EU floor (RA spills chasing it), scalar ABIs,
// no runtime-indexed locals, value-only final eval (fix_sign loss-invariant).
// ---------------------------------------------------------------------------

#define TWOPI_F 6.283185307179586f
#define EPS_Q   1e-12f

// ======================= compile-time J tables =======================
template <int L>
struct JTab { float v[(2*L+1)*(2*L+1)]; };

constexpr double csqrt_c(double x) {
    double g = x > 1.0 ? x : 1.0;
    for (int i = 0; i < 24; ++i) g = 0.5 * (g + x / g);
    return g;
}

// expm((pi/sqrt2)(X0r + X1r)) via A/64, 12-term Taylor, 6 squarings.
// ||A|| <= 2.222*L*sqrt(2)/64 ~ 0.3 -> Taylor-12 error ~1e-17. Matches the
// previously HW-validated on-device fp64 setup kernel (which used /256, 16, 8).
template <int L>
constexpr JTab<L> makeJ() {
    constexpr int n  = 2*L + 1;
    constexpr int nn = n*n;
    double Qre[nn] = {}, Qim[nn] = {};
    const double inv = 0.70710678118654752440;
    for (int i = 0; i < n; ++i) {
        int m = i - L;
        if (m < 0)       { Qre[i*n + (2*L - i)] = inv;      Qim[i*n + i] = -inv; }
        else if (m == 0) { Qre[i*n + L] = 1.0; }
        else {
            double sgn = (m & 1) ? -1.0 : 1.0;
            Qre[i*n + i] = sgn*inv;  Qim[i*n + (2*L - i)] = sgn*inv;
        }
    }
    // off-diagonals of X0c (tridiagonal, complex): sub[r] couples row r to r-1
    double subv[n] = {}, supv[n] = {};
    for (int r = 0; r < n; ++r) {
        const double jj = (double)(L*(L+1));
        if (r > 0) {
            double md = (double)(r - 1 - L);
            subv[r] = -0.5 * csqrt_c(jj - md*(md + 1.0));
        }
        if (r < n - 1) {
            double md = (double)(r - L);
            supv[r] = 0.5 * csqrt_c(jj - md*(md + 1.0));
        }
    }
    // M1 = X0c * Q
    double M1re[nn] = {}, M1im[nn] = {};
    for (int r = 0; r < n; ++r) for (int c = 0; c < n; ++c) {
        double ar = 0.0, ai = 0.0;
        if (r > 0)     { ar += subv[r]*Qre[(r-1)*n+c]; ai += subv[r]*Qim[(r-1)*n+c]; }
        if (r < n - 1) { ar += supv[r]*Qre[(r+1)*n+c]; ai += supv[r]*Qim[(r+1)*n+c]; }
        M1re[r*n+c] = ar; M1im[r*n+c] = ai;
    }
    // X0r = Re(Q^H M1);  A = (pi/sqrt2) * (X0r + X1r) / 64
    double A[nn] = {};
    for (int r = 0; r < n; ++r) for (int c = 0; c < n; ++c) {
        double s = 0.0;
        for (int i = 0; i < n; ++i)
            s += Qre[i*n+r]*M1re[i*n+c] + Qim[i*n+r]*M1im[i*n+c];
        double x1 = ((r + c) == 2*L && r != c) ? (double)(c - L) : 0.0;
        A[r*n+c] = 2.2214414690791831235 * (s + x1) * (1.0/64.0);
    }
    // Taylor: E = I + sum_{k=1..12} A^k/k!
    double E[nn] = {}, T[nn] = {};
    for (int i = 0; i < n; ++i) { E[i*n+i] = 1.0; T[i*n+i] = 1.0; }
    for (int k = 1; k <= 12; ++k) {
        double Tn[nn] = {};
        for (int r = 0; r < n; ++r) for (int c = 0; c < n; ++c) {
            double s = 0.0;
            for (int i = 0; i < n; ++i) s += T[r*n+i]*A[i*n+c];
            Tn[r*n+c] = s / (double)k;
        }
        for (int i = 0; i < nn; ++i) { T[i] = Tn[i]; E[i] += Tn[i]; }
    }
    // 6 squarings (2^6 = 64)
    for (int sq = 0; sq < 6; ++sq) {
        double En[nn] = {};
        for (int r = 0; r < n; ++r) for (int c = 0; c < n; ++c) {
            double s = 0.0;
            for (int i = 0; i < n; ++i) s += E[r*n+i]*E[i*n+c];
            En[r*n+c] = s;
        }
        for (int i = 0; i < nn; ++i) E[i] = En[i];
    }
    JTab<L> out{};
    for (int i = 0; i < nn; ++i) out.v[i] = (float)E[i];
    return out;
}

// separate constexpr evaluations (each well under the constexpr-step limit)
constexpr JTab<4> kJ4h = makeJ<4>();
constexpr JTab<6> kJ6h = makeJ<6>();
__device__ const JTab<4> kJ4 = kJ4h;   // constant-initialized .rodata
__device__ const JTab<6> kJ6 = kJ6h;

// ======================= device helpers =======================
__device__ __forceinline__ bool finitef(float x) {
    return ((__float_as_uint(x) & 0x7f800000u) != 0x7f800000u);
}

// sincos valid for |x| <= ~16 (we use |x| <= 2pi). NaN in -> NaN out.
// (used only in eval_final)
__device__ __forceinline__ void fast_sincos(float x, float& s, float& c) {
    float fk = rintf(x * 0.6366197723675814f);   // x * 2/pi
    int   q  = (int)fk;
    float r  = fmaf(-fk, 1.5703125f, x);
    r = fmaf(-fk, 4.837512969970703125e-4f, r);
    r = fmaf(-fk, 7.549789948768648e-8f, r);
    float z  = r * r;
    float sp = fmaf(fmaf(fmaf(-1.9515295891e-4f, z, 8.3321608736e-3f), z,
                         -1.6666654611e-1f), z * r, r);
    float cp = fmaf(fmaf(fmaf(2.443315711809948e-5f, z, -1.388731625493765e-3f), z,
                         4.166664568298827e-2f), z * z, fmaf(-0.5f, z, 1.0f));
    int qa = q & 3;
    float s0 = (qa & 1) ? cp : sp;
    float c0 = (qa & 1) ? sp : cp;
    if (qa == 1 || qa == 2) c0 = -c0;
    if (qa >= 2)            s0 = -s0;
    s = s0; c = c0;
}

// _normalize_quat value-only, scalar ABI (isfinite -> 0, norm<EPS -> unit)
__device__ __forceinline__ void normalize4(float i0, float i1, float i2, float i3,
                                           float& o0, float& o1, float& o2, float& o3) {
    float a0 = finitef(i0) ? i0 : 0.0f;
    float a1 = finitef(i1) ? i1 : 0.0f;
    float a2 = finitef(i2) ? i2 : 0.0f;
    float a3 = finitef(i3) ? i3 : 0.0f;
    float n = sqrtf(a0*a0 + a1*a1 + a2*a2 + a3*a3);
    if (n < EPS_Q) { o0 = 1.0f; o1 = 0.0f; o2 = 0.0f; o3 = 0.0f; }
    else {
        float mx = fmaxf(n, EPS_Q);
        o0 = a0 / mx; o1 = a1 / mx; o2 = a2 / mx; o3 = a3 / mx;
    }
}

__device__ __forceinline__ void fixsign4(float& q0, float& q1, float& q2, float& q3) {
    if (q0 < 0.0f) { q0 = -q0; q1 = -q1; q2 = -q2; q3 = -q3; }
}

// ---- RotY block rotations with running angle-addition recurrence ----
template <int L>
__device__ __forceinline__ void roty_grad(float* v, float* d, float c1, float s1, float thd) {
    float cm = c1, sm = s1;
#pragma unroll
    for (int m = 1; m <= L; ++m) {
        float fm = (float)m;
        float cd = -fm * sm * thd;
        float sd =  fm * cm * thd;
        float lov = v[L-m], lod = d[L-m], hiv = v[L+m], hid = d[L+m];
        v[L-m] = cm*lov + sm*hiv;
        d[L-m] = cm*lod + cd*lov + sm*hid + sd*hiv;
        v[L+m] = cm*hiv - sm*lov;
        d[L+m] = cm*hid + cd*hiv - sm*lod - sd*lov;
        if (m < L) {
            float cn = cm*c1 - sm*s1;
            float sn = sm*c1 + cm*s1;
            cm = cn; sm = sn;
        }
    }
}

template <int L>
__device__ __forceinline__ void roty_val(float* v, float c1, float s1) {
    float cm = c1, sm = s1;
#pragma unroll
    for (int m = 1; m <= L; ++m) {
        float lov = v[L-m], hiv = v[L+m];
        v[L-m] = cm*lov + sm*hiv;
        v[L+m] = cm*hiv - sm*lov;
        if (m < L) {
            float cn = cm*c1 - sm*s1;
            float sn = sm*c1 + cm*s1;
            cm = cn; sm = sn;
        }
    }
}

// Block-diagonal J matvec over an index LIST (compile-time), grad version.
template <int N, int K>
__device__ __forceinline__ void matvec_list_grad(const int (&idx)[K],
                                                 const float* v, const float* d,
                                                 float* ov, float* od,
                                                 const float* __restrict__ Jm) {
#pragma unroll
    for (int a = 0; a < K; ++a) {
        const int r = idx[a];
        float sv = 0.0f, sd = 0.0f;
#pragma unroll
        for (int b = 0; b < K; ++b) {
            const int c = idx[b];
            float jv = Jm[r*N + c];
            sv = fmaf(jv, v[c], sv);
            sd = fmaf(jv, d[c], sd);
        }
        ov[r] = sv; od[r] = sd;
    }
}

template <int N, int K>
__device__ __forceinline__ void matvec_list_val(const int (&idx)[K],
                                                const float* v, float* ov,
                                                const float* __restrict__ Jm) {
#pragma unroll
    for (int a = 0; a < K; ++a) {
        const int r = idx[a];
        float sv = 0.0f;
#pragma unroll
        for (int b = 0; b < K; ++b) {
            const int c = idx[b];
            sv = fmaf(Jm[r*N + c], v[c], sv);
        }
        ov[r] = sv;
    }
}

// ---------------------------------------------------------------------------
// eval_grad: directional derivative of the loss wrt u[seed]. No loss value,
// no q output, no fix_sign (R(q) quadratic in q: sign flip cancels).
// Cartesian trig; approx rcp/rsq/sqrt builtins (1 instruction each).
// ---------------------------------------------------------------------------
__device__ __forceinline__ float eval_grad(
    float uu0, float uu1, float uu2, float uu3, int seed,
    const float* __restrict__ tgt4, const float* __restrict__ tgt6)
{
    const float* __restrict__ J4g = kJ4.v;
    const float* __restrict__ J6g = kJ6.v;

    // ---- q = normalize(u) with tangent ----
    bool f0 = finitef(uu0), f1 = finitef(uu1), f2 = finitef(uu2), f3 = finitef(uu3);
    float w0 = f0 ? uu0 : 0.0f, w1 = f1 ? uu1 : 0.0f;
    float w2 = f2 ? uu2 : 0.0f, w3 = f3 ? uu3 : 0.0f;
    float wd0 = (f0 && seed == 0) ? 1.0f : 0.0f;
    float wd1 = (f1 && seed == 1) ? 1.0f : 0.0f;
    float wd2 = (f2 && seed == 2) ? 1.0f : 0.0f;
    float wd3 = (f3 && seed == 3) ? 1.0f : 0.0f;
    float ss = w0*w0 + w1*w1 + w2*w2 + w3*w3;
    float n  = __builtin_amdgcn_sqrtf(ss);
    float q0v, q1v, q2v, q3v, q0d, q1d, q2d, q3d;
    if (n < EPS_Q) {
        q0v = 1.f; q1v = 0.f; q2v = 0.f; q3v = 0.f;
        q0d = 0.f; q1d = 0.f; q2d = 0.f; q3d = 0.f;
    } else {
        float rmx = __builtin_amdgcn_rcpf(n);        // n >= EPS here
        float s   = (w0*wd0 + w1*wd1 + w2*wd2 + w3*wd3) * (rmx * rmx);
        q0v = w0 * rmx; q0d = rmx * fmaf(-w0, s, wd0);
        q1v = w1 * rmx; q1d = rmx * fmaf(-w1, s, wd1);
        q2v = w2 * rmx; q2d = rmx * fmaf(-w2, s, wd2);
        q3v = w3 * rmx; q3d = rmx * fmaf(-w3, s, wd3);
    }

    // ---- the 7 rotation-matrix entries we need, with tangents ----
    float R00v = 1.f - 2.f*(q2v*q2v + q3v*q3v);
    float R00d = -4.f*(q2v*q2d + q3v*q3d);
    float R01v = 2.f*(q1v*q2v - q0v*q3v);
    float R01d = 2.f*(q1v*q2d + q1d*q2v - q0v*q3d - q0d*q3v);
    float R02v = 2.f*(q1v*q3v + q0v*q2v);
    float R02d = 2.f*(q1v*q3d + q1d*q3v + q0v*q2d + q0d*q2v);
    float R11v = 1.f - 2.f*(q1v*q1v + q3v*q3v);
    float R11d = -4.f*(q1v*q1d + q3v*q3d);
    float R21v = 2.f*(q2v*q3v + q0v*q1v);
    float R21d = 2.f*(q2v*q3d + q2d*q3v + q0v*q1d + q0d*q1v);
    float R20v = 2.f*(q1v*q3v - q0v*q2v);
    float R20d = 2.f*(q1v*q3d + q1d*q3v - q0v*q2d - q0d*q2v);
    float R22v = 1.f - 2.f*(q1v*q1v + q2v*q2v);
    float R22d = -4.f*(q1v*q1d + q2v*q2d);

    // ---- column normalize + clip (lax balanced-eq tie rule on tangent) ----
    float ss2 = R01v*R01v + R11v*R11v + R21v*R21v;
    float n2  = __builtin_amdgcn_sqrtf(ss2);
    float rn2 = __builtin_amdgcn_rcpf(n2);
    float n2d = (R01v*R01d + R11v*R11d + R21v*R21d) * rn2;
    float mx2 = fmaxf(n2, 1e-12f);
    float rm2 = __builtin_amdgcn_rcpf(mx2);
    float s2  = ((n2 > 1e-12f) ? n2d : 0.0f) * rm2;
    float v0v = R01v * rm2, v0d = rm2 * fmaf(-R01v, s2, R01d);
    float v1v = R11v * rm2, v1d = rm2 * fmaf(-R11v, s2, R11d);
    float v2v = R21v * rm2, v2d = rm2 * fmaf(-R21v, s2, R21d);
    {
        float tv, td;
        tv = v0v; td = v0d;
        td = (tv > -1.0f) ? td : ((tv == -1.0f) ? 0.5f*td : 0.0f);
        tv = (tv > -1.0f) ? tv : -1.0f;
        td = (tv <  1.0f) ? td : ((tv ==  1.0f) ? 0.5f*td : 0.0f);
        tv = (tv <  1.0f) ? tv :  1.0f;
        v0v = tv; v0d = td;
        tv = v1v; td = v1d;
        td = (tv > -1.0f) ? td : ((tv == -1.0f) ? 0.5f*td : 0.0f);
        tv = (tv > -1.0f) ? tv : -1.0f;
        td = (tv <  1.0f) ? td : ((tv ==  1.0f) ? 0.5f*td : 0.0f);
        tv = (tv <  1.0f) ? tv :  1.0f;
        v1v = tv; v1d = td;
        tv = v2v; td = v2d;
        td = (tv > -1.0f) ? td : ((tv == -1.0f) ? 0.5f*td : 0.0f);
        tv = (tv > -1.0f) ? tv : -1.0f;
        td = (tv <  1.0f) ? td : ((tv ==  1.0f) ? 0.5f*td : 0.0f);
        tv = (tv <  1.0f) ? tv :  1.0f;
        v2v = tv; v2d = td;
    }

    // ---- Cartesian trig (no angles ever materialized) ----
    float h2a = v0v*v0v + v2v*v2v;
    float rha = __builtin_amdgcn_rsqf(h2a);
    float sa1 = v0v * rha, ca1 = v2v * rha;
    float amd = (v2v*v0d - v0v*v2d) * (rha * rha);   // NaN/inf at pole = ref
    float omv = 1.0f - v1v*v1v;
    float cb1 = v1v;
    float sb1 = __builtin_amdgcn_sqrtf(omv);
    float bmd = -v1d * __builtin_amdgcn_rsqf(omv);   // -0*inf=NaN, -x*inf=+-inf = ref
    float cad = -sa1*amd, sad = ca1*amd;
    float ynv = ca1*R02v - sa1*R22v;
    float ynd = ca1*R02d + cad*R02v - sa1*R22d - sad*R22v;
    float xdv = ca1*R00v - sa1*R20v;
    float xdd = ca1*R00d + cad*R00v - sa1*R20d - sad*R20v;
    float h2g = ynv*ynv + xdv*xdv;
    float rhg = __builtin_amdgcn_rsqf(h2g);
    float sg1 = ynv * rhg, cg1 = xdv * rhg;
    float gmd = (xdv*ynd - ynv*xdd) * (rhg * rhg);

    // ---- gamma stage: sparse S -> only the m=4 pair rotates ----
    float cg2 = cg1*cg1 - sg1*sg1, sg2 = 2.f*sg1*cg1;
    float cg4 = cg2*cg2 - sg2*sg2, sg4 = 2.f*sg2*cg2;
    float c4d = -4.f*sg4*gmd, s4d = 4.f*cg4*gmd;

    constexpr int P4p[5] = {1,3,4,6,8};
    constexpr int P4m[4] = {0,2,5,7};
    constexpr int P6p[7] = {1,3,5,6,8,10,12};
    constexpr int P6m[6] = {0,2,4,7,9,11};

    // ---- both chains, stage-interleaved (independent: free ILP) ----
    float u4v[9], u4d[9], u6v[13], u6d[13];
    {
        const float hi4 = 0.6455f, ce4 = 0.7638f;
        float t0v = sg4*hi4, t0d = s4d*hi4;
        float t8v = cg4*hi4, t8d = c4d*hi4;
#pragma unroll
        for (int a = 0; a < 4; ++a) {
            const int r = P4m[a];
            float j0 = J4g[r*9+0];
            u4v[r] = j0 * t0v;
            u4d[r] = j0 * t0d;
        }
#pragma unroll
        for (int a = 0; a < 5; ++a) {
            const int r = P4p[a];
            float j4 = J4g[r*9+4], j8 = J4g[r*9+8];
            u4v[r] = fmaf(j4, ce4, j8*t8v);
            u4d[r] = j8 * t8d;
        }
        const float hi6 = -0.9354f, ce6 = 0.3536f;
        float t2v = sg4*hi6,  t2d = s4d*hi6;
        float t10v = cg4*hi6, t10d = c4d*hi6;
#pragma unroll
        for (int a = 0; a < 6; ++a) {
            const int r = P6m[a];
            float j2 = J6g[r*13+2];
            u6v[r] = j2 * t2v;
            u6d[r] = j2 * t2d;
        }
#pragma unroll
        for (int a = 0; a < 7; ++a) {
            const int r = P6p[a];
            float j6 = J6g[r*13+6], j10 = J6g[r*13+10];
            u6v[r] = fmaf(j6, ce6, j10*t10v);
            u6d[r] = j10 * t10d;
        }
    }
    roty_grad<4>(u4v, u4d, cb1, sb1, bmd);
    roty_grad<6>(u6v, u6d, cb1, sb1, bmd);
    float p4v[9], p4d[9], p6v[13], p6d[13];
    matvec_list_grad<9,4>(P4m, u4v, u4d, p4v, p4d, J4g);
    matvec_list_grad<9,5>(P4p, u4v, u4d, p4v, p4d, J4g);
    matvec_list_grad<13,6>(P6m, u6v, u6d, p6v, p6d, J6g);
    matvec_list_grad<13,7>(P6p, u6v, u6d, p6v, p6d, J6g);
    roty_grad<4>(p4v, p4d, ca1, sa1, amd);
    roty_grad<6>(p6v, p6d, ca1, sa1, amd);

    float g4s = 0.f, g6s = 0.f;
#pragma unroll
    for (int i = 0; i < 9; ++i) {
        float d = p4v[i] - tgt4[i];
        g4s = fmaf(d, p4d[i], g4s);
    }
#pragma unroll
    for (int i = 0; i < 13; ++i) {
        float d = p6v[i] - tgt6[i];
        g6s = fmaf(d, p6d[i], g6s);
    }
    return 2.0f * g4s / 9.0f + g6s / 13.0f;   // (2/9)g4 + 0.5*(2/13)g6
}

// ---------------------------------------------------------------------------
// eval_final: VALUE ONLY -- loss and q = fix_sign(normalize(u)).
// Keeps the libm/ref-shaped path (runs once; argmin stability).
// ---------------------------------------------------------------------------
__device__ __forceinline__ void eval_final(
    float uu0, float uu1, float uu2, float uu3,
    const float* __restrict__ tgt4, const float* __restrict__ tgt6,
    float& loss_out, float& q0o, float& q1o, float& q2o, float& q3o)
{
    const float* __restrict__ J4g = kJ4.v;
    const float* __restrict__ J6g = kJ6.v;

    float q0v, q1v, q2v, q3v;
    normalize4(uu0, uu1, uu2, uu3, q0v, q1v, q2v, q3v);
    fixsign4(q0v, q1v, q2v, q3v);
    q0o = q0v; q1o = q1v; q2o = q2v; q3o = q3v;

    float R00v = 1.f - 2.f*(q2v*q2v + q3v*q3v);
    float R01v = 2.f*(q1v*q2v - q0v*q3v);
    float R02v = 2.f*(q1v*q3v + q0v*q2v);
    float R11v = 1.f - 2.f*(q1v*q1v + q3v*q3v);
    float R21v = 2.f*(q2v*q3v + q0v*q1v);
    float R20v = 2.f*(q1v*q3v - q0v*q2v);
    float R22v = 1.f - 2.f*(q1v*q1v + q2v*q2v);

    float n2  = sqrtf(R01v*R01v + R11v*R11v + R21v*R21v);
    float mx2 = fmaxf(n2, 1e-12f);
    float v0v = fminf(fmaxf(R01v / mx2, -1.0f), 1.0f);
    float v1v = fminf(fmaxf(R11v / mx2, -1.0f), 1.0f);
    float v2v = fminf(fmaxf(R21v / mx2, -1.0f), 1.0f);

    float bAv = acosf(v1v);
    float aAv = atan2f(v0v, v2v);
    float sav, cav;
    fast_sincos(aAv, sav, cav);
    float ynv = cav*R02v - sav*R22v;
    float xdv = cav*R00v - sav*R20v;
    float cCv = atan2f(ynv, xdv);

    float amv = (aAv < 0.0f) ? aAv + TWOPI_F : aAv;
    float bmv = bAv;
    float gmv = (cCv < 0.0f) ? cCv + TWOPI_F : cCv;

    float sa1, ca1, sb1, cb1, sg1, cg1;
    fast_sincos(amv, sa1, ca1);
    fast_sincos(bmv, sb1, cb1);
    fast_sincos(gmv, sg1, cg1);

    float cg2 = cg1*cg1 - sg1*sg1, sg2 = 2.f*sg1*cg1;
    float cg4 = cg2*cg2 - sg2*sg2, sg4 = 2.f*sg2*cg2;

    constexpr int P4p[5] = {1,3,4,6,8};
    constexpr int P4m[4] = {0,2,5,7};
    constexpr int P6p[7] = {1,3,5,6,8,10,12};
    constexpr int P6m[6] = {0,2,4,7,9,11};

    float loss;
    {   // l = 4
        float u4v[9];
        const float hi = 0.6455f, ce = 0.7638f;
        float t0v = sg4*hi, t8v = cg4*hi;
#pragma unroll
        for (int a = 0; a < 4; ++a) {
            const int r = P4m[a];
            u4v[r] = J4g[r*9+0] * t0v;
        }
#pragma unroll
        for (int a = 0; a < 5; ++a) {
            const int r = P4p[a];
            u4v[r] = fmaf(J4g[r*9+4], ce, J4g[r*9+8]*t8v);
        }
        roty_val<4>(u4v, cb1, sb1);
        float p4v[9];
        matvec_list_val<9,4>(P4m, u4v, p4v, J4g);
        matvec_list_val<9,5>(P4p, u4v, p4v, J4g);
        roty_val<4>(p4v, ca1, sa1);
        float s4s = 0.f;
#pragma unroll
        for (int i = 0; i < 9; ++i) {
            float d = p4v[i] - tgt4[i];
            s4s = fmaf(d, d, s4s);
        }
        loss = s4s / 9.0f;
    }
    {   // l = 6
        float u6v[13];
        const float hi = -0.9354f, ce = 0.3536f;
        float t2v = sg4*hi, t10v = cg4*hi;
#pragma unroll
        for (int a = 0; a < 6; ++a) {
            const int r = P6m[a];
            u6v[r] = J6g[r*13+2] * t2v;
        }
#pragma unroll
        for (int a = 0; a < 7; ++a) {
            const int r = P6p[a];
            u6v[r] = fmaf(J6g[r*13+6], ce, J6g[r*13+10]*t10v);
        }
        roty_val<6>(u6v, cb1, sb1);
        float p6v[13];
        matvec_list_val<13,6>(P6m, u6v, p6v, J6g);
        matvec_list_val<13,7>(P6p, u6v, p6v, J6g);
        roty_val<6>(p6v, ca1, sa1);
        float s6s = 0.f;
#pragma unroll
        for (int i = 0; i < 13; ++i) {
            float d = p6v[i] - tgt6[i];
            s6s = fmaf(d, d, s6s);
        }
        loss += 0.5f * (s6s / 13.0f);
    }
    loss_out = loss;
}

// ---------------------------------------------------------------------------
// Main kernel: 192 threads = 48 instances (4 lanes each) = 8 batch elements.
// ---------------------------------------------------------------------------
__global__ __launch_bounds__(192) void opt_kernel(
    const float* __restrict__ f4, const float* __restrict__ f6,
    const float* __restrict__ qr, float* __restrict__ out)
{
    __shared__ float tg4[8 * 9], tg6[8 * 13];
    __shared__ float selL[48], selQ[48 * 4];

    const int tid = threadIdx.x;
    for (int i = tid; i < 72;  i += 192) tg4[i] = f4[blockIdx.x * 72  + i];
    for (int i = tid; i < 104; i += 192) tg6[i] = f6[blockIdx.x * 104 + i];
    __syncthreads();

    const int inst = tid >> 2;          // 0..47
    const int lane = tid & 3;           // tangent seed / Adam component
    const int gi   = blockIdx.x * 48 + inst;
    const int e    = gi / 6;
    const int k    = gi % 6;
    const int eloc = inst / 6;          // 0..7

    // targets into registers (22 VGPR; was 22 ds_reads per eval)
    float t4r[9], t6r[13];
#pragma unroll
    for (int i = 0; i < 9; ++i)  t4r[i] = tg4[eloc * 9 + i];
#pragma unroll
    for (int i = 0; i < 13; ++i) t6r[i] = tg6[eloc * 13 + i];

    // ---- init u = fix_sign(normalize(concat(first, normalize(q_rand)))) ----
    float u0, u1, u2, u3;
    {
        float t0, t1, t2, t3;
        if (k == 0) {
            t0 = 1.0f; t1 = 0.0f; t2 = 0.0f; t3 = 0.0f;
        } else {
            const float* rp = &qr[(e * 5 + (k - 1)) * 4];
            normalize4(rp[0], rp[1], rp[2], rp[3], t0, t1, t2, t3);
        }
        normalize4(t0, t1, t2, t3, u0, u1, u2, u3);
        fixsign4(u0, u1, u2, u3);
    }

    float mAd = 0.0f, vAd = 0.0f;
    float b1p = 1.0f, b2p = 1.0f;
    const int base = tid & 60;          // lane-quad base within the 64-wide wave

#pragma unroll 1
    for (int step = 0; step < 25; ++step) {
        float dl = eval_grad(u0, u1, u2, u3, lane, t4r, t6r);
        float g = dl * (1.0f / 49152.0f);   // jnp.mean over bsz*k instances
        b1p *= 0.9f; b2p *= 0.999f;
        mAd = 0.9f   * mAd + 0.1f   * g;
        vAd = 0.999f * vAd + 0.001f * g * g;
        float mh = mAd / (1.0f - b1p);
        float vh = vAd / (1.0f - b2p);
        float comp = (lane == 0) ? u0 : (lane == 1) ? u1 : (lane == 2) ? u2 : u3;
        float un = comp - 0.08f * mh / (sqrtf(vh) + 1e-8f);
        u0 = __shfl(un, base + 0, 64);
        u1 = __shfl(un, base + 1, 64);
        u2 = __shfl(un, base + 2, 64);
        u3 = __shfl(un, base + 3, 64);
    }

    float lossF, qf0, qf1, qf2, qf3;
    eval_final(u0, u1, u2, u3, t4r, t6r, lossF, qf0, qf1, qf2, qf3);

    if (lane == 0) {
        selL[inst] = lossF;
        selQ[inst * 4 + 0] = qf0; selQ[inst * 4 + 1] = qf1;
        selQ[inst * 4 + 2] = qf2; selQ[inst * 4 + 3] = qf3;
    }
    __syncthreads();

    // ---- per-element argmin over 6 starts + final fix_sign(normalize()) ----
    if (tid < 8) {
        int b0 = tid * 6, best = 0;
        float bl = selL[b0];
#pragma unroll
        for (int kk = 1; kk < 6; ++kk) {
            float v = selL[b0 + kk];
            if (v < bl) { bl = v; best = kk; }
        }
        float o0, o1, o2, o3;
        normalize4(selQ[(b0 + best) * 4 + 0], selQ[(b0 + best) * 4 + 1],
                   selQ[(b0 + best) * 4 + 2], selQ[(b0 + best) * 4 + 3],
                   o0, o1, o2, o3);
        fixsign4(o0, o1, o2, o3);
        int eo = blockIdx.x * 8 + tid;
        out[eo * 4 + 0] = o0; out[eo * 4 + 1] = o1;
        out[eo * 4 + 2] = o2; out[eo * 4 + 3] = o3;
    }
}

extern "C" void kernel_launch(void* const* d_in, const int* in_sizes, int n_in,
                              void* d_out, int out_size, void* d_ws, size_t ws_size,
                              hipStream_t stream) {
    const float* f4 = (const float*)d_in[0];   // (8192, 9)
    const float* f6 = (const float*)d_in[1];   // (8192, 13)
    const float* qr = (const float*)d_in[2];   // (8192, 5, 4)
    float* out = (float*)d_out;                // (8192, 4)
    (void)d_ws; (void)ws_size;                 // J is compile-time now

    opt_kernel<<<1024, 192, 0, stream>>>(f4, f6, qr, out);
}